// Round 16
// baseline (190.579 us; speedup 1.0000x reference)
//
#include <hip/hip_runtime.h>
#include <hip/hip_fp16.h>

#define D 64
#define BSH 9                   // 512 nodes per coarse bucket
#define BSZ (1 << BSH)
#define PB 4096                 // edges per pass-1 block (512 thr x 8)
#define CAPR 10240              // per-bucket raw capacity (int2 units; ~+23 sigma)
#define FASTU (BSZ * 32)        // 16384 uints of fast slots per bucket

// init per-bucket cursors to raw region bases (int2 units); ccur[255] = ext counter
__global__ __launch_bounds__(256) void initcur(int* __restrict__ ccur, int nbuck) {
    int t = threadIdx.x;
    if (t < nbuck) ccur[t] = t * CAPR;
    if (t == 255) ccur[255] = 0;
}

// pass 1: block-local counting sort into coarse buckets; coalesced run writes.
// raw edge: x = src | (dst&511)<<17 ; y = bits(ew)
__global__ __launch_bounds__(512) void bucket1(const int* __restrict__ src,
                                               const int* __restrict__ dst,
                                               const float* __restrict__ ew,
                                               int* __restrict__ ccur,
                                               int2* __restrict__ pairs2,
                                               int E, int nbuck) {
    __shared__ int hist[512];
    __shared__ int lbase[512];
    __shared__ int gbase[512];
    __shared__ int wsum[8];
    __shared__ int w0s[PB];
    __shared__ int w1s[PB];
    __shared__ unsigned char bids[PB];
    int t = threadIdx.x;
    hist[t] = 0;
    __syncthreads();
    int e0 = blockIdx.x * PB;
    int cnt = min(PB, E - e0);
    int b[8], lr[8], w0[8], w1[8];
    int i8 = t * 8;
    bool full8 = (i8 + 8 <= cnt);
    if (full8) {
        int4   sa = *(const int4*)&src[e0 + i8];
        int4   sb = *(const int4*)&src[e0 + i8 + 4];
        int4   da = *(const int4*)&dst[e0 + i8];
        int4   db = *(const int4*)&dst[e0 + i8 + 4];
        float4 wa = *(const float4*)&ew[e0 + i8];
        float4 wb = *(const float4*)&ew[e0 + i8 + 4];
        int ss[8] = {sa.x, sa.y, sa.z, sa.w, sb.x, sb.y, sb.z, sb.w};
        int ds[8] = {da.x, da.y, da.z, da.w, db.x, db.y, db.z, db.w};
        float wv[8] = {wa.x, wa.y, wa.z, wa.w, wb.x, wb.y, wb.z, wb.w};
#pragma unroll
        for (int k = 0; k < 8; ++k) {
            b[k]  = ds[k] >> BSH;
            w0[k] = ss[k] | ((ds[k] & (BSZ - 1)) << 17);
            w1[k] = __float_as_int(wv[k]);
            lr[k] = atomicAdd(&hist[b[k]], 1);
        }
    } else {
#pragma unroll
        for (int k = 0; k < 8; ++k) {
            int idx = i8 + k;
            if (idx < cnt) {
                int d = dst[e0 + idx];
                b[k]  = d >> BSH;
                w0[k] = src[e0 + idx] | ((d & (BSZ - 1)) << 17);
                w1[k] = __float_as_int(ew[e0 + idx]);
                lr[k] = atomicAdd(&hist[b[k]], 1);
            }
        }
    }
    __syncthreads();
    int hv = hist[t];
    // wave-level shfl scan (2 barriers instead of 18)
    int lane = t & 63, wv8 = t >> 6;
    int s = hv;
#pragma unroll
    for (int off = 1; off < 64; off <<= 1) {
        int u = __shfl_up(s, off, 64);
        if (lane >= off) s += u;
    }
    if (lane == 63) wsum[wv8] = s;
    __syncthreads();
    int woff = 0;
#pragma unroll
    for (int w = 0; w < 8; ++w) { int x = wsum[w]; if (w < wv8) woff += x; }
    int excl = s + woff - hv;
    lbase[t] = excl;
    if (t < nbuck && hv > 0) gbase[t] = atomicAdd(&ccur[t], hv);
    __syncthreads();
#pragma unroll
    for (int k = 0; k < 8; ++k) {
        int idx = i8 + k;
        if (idx < cnt) {
            int slot = lbase[b[k]] + lr[k];
            w0s[slot] = w0[k];
            w1s[slot] = w1[k];
            bids[slot] = (unsigned char)b[k];
        }
    }
    __syncthreads();
    for (int i = t; i < cnt; i += 512) {
        int bb = bids[i];
        int pos = gbase[bb] + (i - lbase[bb]);
        pairs2[pos] = make_int2(w0s[i], w1s[i]);
    }
}

// fused pass 2, de-staged: two global passes over the bucket (L2-resident, 80KB).
// pass A: per-node counts + degree sums. pass B: fresh-rank scatter to separate
// fastU table. adaptive pad 16/32(+ext). LDS only 8KB -> high occupancy.
__global__ __launch_bounds__(512) void sort2(const int2* __restrict__ pairs2,
                                             unsigned int* __restrict__ fastU,
                                             const int* __restrict__ ccur,
                                             int2* __restrict__ extRng,
                                             unsigned int* __restrict__ extU,
                                             int* __restrict__ gext,
                                             float* __restrict__ dis,
                                             int N, int nbuck) {
    __shared__ int cnt[512];
    __shared__ float sdeg[512];
    __shared__ int cur[512];
    __shared__ int ebase[512];
    int b = blockIdx.x;
    int t = threadIdx.x;
    int baseR = b * CAPR;          // raw int2 units
    int baseF = b * FASTU;         // fast-table uint units
    int cntb = min(ccur[b] - baseR, CAPR);
    cnt[t] = 0;
    sdeg[t] = 0.0f;
    cur[t] = 0;
    __syncthreads();
    for (int i = t; i < cntb; i += 512) {
        int2 p = pairs2[baseR + i];
        int dl = (p.x >> 17) & (BSZ - 1);
        atomicAdd(&cnt[dl], 1);
        atomicAdd(&sdeg[dl], __int_as_float(p.y));
    }
    __syncthreads();
    int node = (b << BSH) + t;
    int cntv = cnt[t];
    int tot  = cntv + 1;                       // +1 self-edge
    int pc   = (tot <= 16) ? 16 : ((tot + 31) & ~31);
    int extLen = (pc > 32) ? (pc - 32) : 0;
    int extBase = 0;
    if (node < N && extLen > 0) extBase = atomicAdd(gext, extLen);  // rare
    float dloc = rsqrtf(sdeg[t] + 1.0f);
    __syncthreads();
    sdeg[t]  = dloc;               // bucket-local dis
    ebase[t] = extBase;
    if (node < N) {
        int flag = (pc == 16) ? (1 << 30) : 0;
        extRng[node] = make_int2(extBase | flag, extBase + extLen);
        dis[node]    = dloc;
    }
    // zero-fill this bucket's fast region (coalesced)
    for (int i = t; i < FASTU; i += 512) fastU[baseF + i] = 0u;
    __syncthreads();
    for (int i = t; i < cntb; i += 512) {
        int2 p = pairs2[baseR + i];
        int dl = (p.x >> 17) & (BSZ - 1);
        int s  = p.x & 0x1FFFF;
        int rank = atomicAdd(&cur[dl], 1);     // fresh ranks (uniqueness suffices)
        float w = __int_as_float(p.y) * sdeg[dl];   // ew * dis[dst]
        unsigned int h = (unsigned int)__half_as_ushort(__float2half_rn(w));
        unsigned int packed = ((unsigned int)s << 15) | ((h + 1u) >> 1);
        if (rank < 32) fastU[baseF + dl * 32 + rank] = packed;
        else           extU[ebase[dl] + rank - 32]   = packed;
    }
    __syncthreads();
    if (node < N) {
        unsigned int h = (unsigned int)__half_as_ushort(__float2half_rn(dloc));
        unsigned int selfp = ((unsigned int)node << 15) | ((h + 1u) >> 1);
        if (cntv < 32) fastU[baseF + t * 32 + cntv] = selfp;
        else           extU[extBase + cntv - 32]    = selfp;
        for (int i = cntv + 1 - 32; i < extLen; ++i) extU[extBase + i] = 0u;
    }
}

// Hb = dis * (X @ W) -> fp16; X is fp32 (layer 1) or fp16 (layer 2)
template<int HIN>
__global__ __launch_bounds__(256) void gemm64h(const void* __restrict__ Xv,
                                               const float* __restrict__ W,
                                               const float* __restrict__ dis,
                                               __half* __restrict__ Hb, int n) {
    __shared__ float Ws[64 * 64];
    __shared__ float Xs[16 * 64];
    for (int t = threadIdx.x; t < 64 * 64; t += 256) Ws[t] = W[t];
    int row0 = blockIdx.x * 16;
    for (int t = threadIdx.x; t < 16 * 64; t += 256) {
        int r = row0 + (t >> 6);
        float v = 0.0f;
        if (r < n) {
            if constexpr (HIN) v = __half2float(((const __half*)Xv)[r * 64 + (t & 63)]);
            else               v = ((const float*)Xv)[r * 64 + (t & 63)];
        }
        Xs[t] = v;
    }
    __syncthreads();
    int r  = threadIdx.x >> 4;
    int jc = (threadIdx.x & 15) * 4;
    float4 acc = make_float4(0.f, 0.f, 0.f, 0.f);
#pragma unroll
    for (int k = 0; k < 64; ++k) {
        float xv = Xs[r * 64 + k];
        float4 w = *(const float4*)&Ws[k * 64 + jc];
        acc.x += xv * w.x; acc.y += xv * w.y; acc.z += xv * w.z; acc.w += xv * w.w;
    }
    int rr = row0 + r;
    if (rr < n) {
        float ds = dis[rr];
        ushort4 pk;
        pk.x = __half_as_ushort(__float2half(ds * acc.x));
        pk.y = __half_as_ushort(__float2half(ds * acc.y));
        pk.z = __half_as_ushort(__float2half(ds * acc.z));
        pk.w = __half_as_ushort(__float2half(ds * acc.w));
        *(ushort4*)&Hb[rr * 64 + jc] = pk;
    }
}

// accumulate one 32-slot ext group (fp16 packed, 4 independent row gathers)
__device__ __forceinline__ void acc_group(unsigned int pv, int g, int fl,
                                          const __half* __restrict__ Hb,
                                          __half2 a0[4], __half2 a1[4],
                                          __half2 a2[4], __half2 a3[4]) {
    unsigned int q0 = __shfl(pv, g, 64);
    unsigned int q1 = __shfl(pv, g + 8, 64);
    unsigned int q2 = __shfl(pv, g + 16, 64);
    unsigned int q3 = __shfl(pv, g + 24, 64);
    uint4 r0 = *(const uint4*)(Hb + (size_t)(q0 >> 15) * 64 + fl);
    uint4 r1 = *(const uint4*)(Hb + (size_t)(q1 >> 15) * 64 + fl);
    uint4 r2 = *(const uint4*)(Hb + (size_t)(q2 >> 15) * 64 + fl);
    uint4 r3 = *(const uint4*)(Hb + (size_t)(q3 >> 15) * 64 + fl);
    __half2 w0 = __half2half2(__ushort_as_half((unsigned short)((q0 & 0x7FFFu) << 1)));
    __half2 w1 = __half2half2(__ushort_as_half((unsigned short)((q1 & 0x7FFFu) << 1)));
    __half2 w2 = __half2half2(__ushort_as_half((unsigned short)((q2 & 0x7FFFu) << 1)));
    __half2 w3 = __half2half2(__ushort_as_half((unsigned short)((q3 & 0x7FFFu) << 1)));
    const __half2* h0 = (const __half2*)&r0;
    const __half2* h1 = (const __half2*)&r1;
    const __half2* h2 = (const __half2*)&r2;
    const __half2* h3 = (const __half2*)&r3;
#pragma unroll
    for (int k = 0; k < 4; ++k) {
        a0[k] = __hfma2(w0, h0[k], a0[k]);
        a1[k] = __hfma2(w1, h1[k], a1[k]);
        a2[k] = __hfma2(w2, h2[k], a2[k]);
        a3[k] = __hfma2(w3, h3[k], a3[k]);
    }
}

// main 32-slot accumulation with adaptive small-node row skip
__device__ __forceinline__ void acc_main(unsigned int pv, bool small, int g, int fl,
                                         const __half* __restrict__ Hb,
                                         __half2 a0[4], __half2 a1[4],
                                         __half2 a2[4], __half2 a3[4]) {
    unsigned int q0 = __shfl(pv, g, 64);
    unsigned int q1 = __shfl(pv, g + 8, 64);
    unsigned int q2 = __shfl(pv, g + 16, 64);
    unsigned int q3 = __shfl(pv, g + 24, 64);
    uint4 r0 = *(const uint4*)(Hb + (size_t)(q0 >> 15) * 64 + fl);
    uint4 r1 = *(const uint4*)(Hb + (size_t)(q1 >> 15) * 64 + fl);
    uint4 r2, r3;
    if (!small) {
        r2 = *(const uint4*)(Hb + (size_t)(q2 >> 15) * 64 + fl);
        r3 = *(const uint4*)(Hb + (size_t)(q3 >> 15) * 64 + fl);
    }
    __half2 w0 = __half2half2(__ushort_as_half((unsigned short)((q0 & 0x7FFFu) << 1)));
    __half2 w1 = __half2half2(__ushort_as_half((unsigned short)((q1 & 0x7FFFu) << 1)));
    const __half2* h0 = (const __half2*)&r0;
    const __half2* h1 = (const __half2*)&r1;
#pragma unroll
    for (int k = 0; k < 4; ++k) {
        a0[k] = __hfma2(w0, h0[k], a0[k]);
        a1[k] = __hfma2(w1, h1[k], a1[k]);
    }
    if (!small) {
        __half2 w2 = __half2half2(__ushort_as_half((unsigned short)((q2 & 0x7FFFu) << 1)));
        __half2 w3 = __half2half2(__ushort_as_half((unsigned short)((q3 & 0x7FFFu) << 1)));
        const __half2* h2 = (const __half2*)&r2;
        const __half2* h3 = (const __half2*)&r3;
#pragma unroll
        for (int k = 0; k < 4; ++k) {
            a2[k] = __hfma2(w2, h2[k], a2[k]);
            a3[k] = __hfma2(w3, h3[k], a3[k]);
        }
    }
}

// fp16 butterfly + relu store (lanes g<2)
template<int HOUT>
__device__ __forceinline__ void finish_node(__half2 a0[4], __half2 a1[4],
                                            __half2 a2[4], __half2 a3[4],
                                            int g, int fl,
                                            void* __restrict__ OUTv, int node) {
    __half2 a[4];
#pragma unroll
    for (int k = 0; k < 4; ++k)
        a[k] = __hadd2(__hadd2(a0[k], a1[k]), __hadd2(a2[k], a3[k]));
#pragma unroll
    for (int m = 8; m < 64; m <<= 1) {
#pragma unroll
        for (int k = 0; k < 4; ++k) {
            unsigned u = __shfl_xor(*(unsigned*)&a[k], m, 64);
            a[k] = __hadd2(a[k], *(__half2*)&u);
        }
    }
    if (g < 2) {
        int o = g * 2;
        float2 f0 = __half22float2(a[o]);
        float2 f1 = __half22float2(a[o + 1]);
        float rx = fmaxf(f0.x, 0.0f), ry = fmaxf(f0.y, 0.0f);
        float rz = fmaxf(f1.x, 0.0f), rw = fmaxf(f1.y, 0.0f);
        if constexpr (HOUT) {
            ushort4 pk;
            pk.x = __half_as_ushort(__float2half(rx));
            pk.y = __half_as_ushort(__float2half(ry));
            pk.z = __half_as_ushort(__float2half(rz));
            pk.w = __half_as_ushort(__float2half(rw));
            *(ushort4*)&((__half*)OUTv)[node * 64 + fl + g * 4] = pk;
        } else {
            float4 vv = make_float4(rx, ry, rz, rw);
            *(float4*)&((float*)OUTv)[node * 64 + fl + g * 4] = vv;
        }
    }
}

// 2 nodes per wave: node1's fastU/extRng loads issued at wave start (latency
// hidden under node0's rows+FMA); node1 rows overlap node0's butterfly.
// !h1 handled via zero-weight dummy (pv=0 -> w=0, gathers row 0 harmlessly).
template<int HOUT>
__global__ __launch_bounds__(256) void gather64(const unsigned int* __restrict__ fastU,
                                                const unsigned int* __restrict__ extU,
                                                const int2* __restrict__ extRng,
                                                const __half* __restrict__ Hb,
                                                void* __restrict__ OUTv, int N) {
    int wv = threadIdx.x >> 6;
    int node0 = blockIdx.x * 8 + wv;
    if (node0 >= N) return;
    int node1 = node0 + 4;
    bool h1 = (node1 < N);
    int lane = threadIdx.x & 63;
    int g    = lane >> 3;
    int fl   = (lane & 7) * 8;
    int l31  = lane & 31;
    int f0 = (node0 >> BSH) * FASTU + (node0 & (BSZ - 1)) * 32;
    unsigned int pv0 = fastU[f0 + l31];
    int2 er0 = extRng[node0];
    int f1 = (node1 >> BSH) * FASTU + (node1 & (BSZ - 1)) * 32;
    unsigned int pv1 = h1 ? fastU[f1 + l31] : 0u;
    int2 er1 = h1 ? extRng[node1] : make_int2(1 << 30, 0);
    bool small0 = (er0.x & (1 << 30)) != 0;
    bool small1 = (er1.x & (1 << 30)) != 0;
    int eb0 = er0.x & 0x3FFFFFFF;
    int eb1 = er1.x & 0x3FFFFFFF;
    __half2 z = __float2half2_rn(0.0f);
    __half2 A0[4] = {z, z, z, z}, A1[4] = {z, z, z, z};
    __half2 A2[4] = {z, z, z, z}, A3[4] = {z, z, z, z};
    __half2 B0[4] = {z, z, z, z}, B1[4] = {z, z, z, z};
    __half2 B2[4] = {z, z, z, z}, B3[4] = {z, z, z, z};
    acc_main(pv0, small0, g, fl, Hb, A0, A1, A2, A3);
    for (int e = eb0; e < er0.y; e += 32)     // rare overflow tail
        acc_group(extU[e + l31], g, fl, Hb, A0, A1, A2, A3);
    acc_main(pv1, small1, g, fl, Hb, B0, B1, B2, B3);
    for (int e = eb1; e < er1.y; e += 32)     // rare overflow tail
        acc_group(extU[e + l31], g, fl, Hb, B0, B1, B2, B3);
    finish_node<HOUT>(A0, A1, A2, A3, g, fl, OUTv, node0);
    if (h1) finish_node<HOUT>(B0, B1, B2, B3, g, fl, OUTv, node1);
}

extern "C" void kernel_launch(void* const* d_in, const int* in_sizes, int n_in,
                              void* d_out, int out_size, void* d_ws, size_t ws_size,
                              hipStream_t stream) {
    const float* x  = (const float*)d_in[0];
    const int*   ei = (const int*)d_in[1];   // [2, E] int32
    const float* ew = (const float*)d_in[2];
    const float* W0 = (const float*)d_in[3];
    const float* W1 = (const float*)d_in[4];
    float* out = (float*)d_out;

    const int N = in_sizes[0] / D;           // 100000
    const int E = in_sizes[2];               // 1600000
    const int* src = ei;
    const int* dst = ei + E;

    const int nbuck = (N + BSZ - 1) >> BSH;  // 196
    const int Na = (N + 1 + 255) & ~255;

    // layout (ints): dis[Na] | extRng[2*Na] | ccur[1024] |
    //                pairs2 raw [nbuck*CAPR int2] (x1h aliases after sort2) |
    //                fastU [nbuck*FASTU uints] | Hb[64N halves] | extU[262144]
    float* dis     = (float*)d_ws;
    int2*  extRng  = (int2*)((int*)d_ws + Na);
    int*   ccur    = (int*)d_ws + 3 * Na;
    int2*  pairs2  = (int2*)((int*)d_ws + 3 * Na + 1024);
    unsigned int* fastU = (unsigned int*)(pairs2 + (size_t)nbuck * CAPR);
    __half* Hb     = (__half*)(fastU + (size_t)nbuck * FASTU);
    unsigned int* extU = (unsigned int*)(Hb + (size_t)N * D);
    __half* x1h    = (__half*)pairs2;        // aliases raw (dead after sort2)

    const int nb1 = (E + PB - 1) / PB;       // 391

    // --- build node-sorted, norm-folded, packed, fixed-slot edge table + dis ---
    initcur<<<1, 256, 0, stream>>>(ccur, nbuck);
    bucket1<<<nb1, 512, 0, stream>>>(src, dst, ew, ccur, pairs2, E, nbuck);
    sort2<<<nbuck, 512, 0, stream>>>(pairs2, fastU, ccur, extRng, extU,
                                     ccur + 255, dis, N, nbuck);

    const int gemm_grid   = (N + 15) / 16;
    const int gather_grid = (N + 7) / 8;     // 2 nodes per wave

    // --- layer 1: fp16 intermediate x1h ---
    gemm64h<0><<<gemm_grid, 256, 0, stream>>>(x, W0, dis, Hb, N);
    gather64<1><<<gather_grid, 256, 0, stream>>>(fastU, extU, extRng, Hb, x1h, N);

    // --- layer 2: fp32 output ---
    gemm64h<1><<<gemm_grid, 256, 0, stream>>>(x1h, W1, dis, Hb, N);
    gather64<0><<<gather_grid, 256, 0, stream>>>(fastU, extU, extRng, Hb, out, N);
}

// Round 17
// 188.992 us; speedup vs baseline: 1.0084x; 1.0084x over previous
//
#include <hip/hip_runtime.h>
#include <hip/hip_fp16.h>

#define D 64
#define BSH 9                   // 512 nodes per coarse bucket
#define BSZ (1 << BSH)
#define PB 4096                 // edges per pass-1 block (512 thr x 8)
#define CAPR 10240              // per-bucket raw capacity (int2 units; ~+23 sigma)
#define FASTU (BSZ * 32)        // 16384 uints of fast slots per bucket

// init per-bucket cursors to raw region bases (int2 units); ccur[255] = ext counter
__global__ __launch_bounds__(256) void initcur(int* __restrict__ ccur, int nbuck) {
    int t = threadIdx.x;
    if (t < nbuck) ccur[t] = t * CAPR;
    if (t == 255) ccur[255] = 0;
}

// pass 1: block-local counting sort into coarse buckets; coalesced run writes.
// raw edge: x = src | (dst&511)<<17 ; y = bits(ew)
__global__ __launch_bounds__(512) void bucket1(const int* __restrict__ src,
                                               const int* __restrict__ dst,
                                               const float* __restrict__ ew,
                                               int* __restrict__ ccur,
                                               int2* __restrict__ pairs2,
                                               int E, int nbuck) {
    __shared__ int hist[512];
    __shared__ int lbase[512];
    __shared__ int gbase[512];
    __shared__ int wsum[8];
    __shared__ int w0s[PB];
    __shared__ int w1s[PB];
    __shared__ unsigned char bids[PB];
    int t = threadIdx.x;
    hist[t] = 0;
    __syncthreads();
    int e0 = blockIdx.x * PB;
    int cnt = min(PB, E - e0);
    int b[8], lr[8], w0[8], w1[8];
    int i8 = t * 8;
    bool full8 = (i8 + 8 <= cnt);
    if (full8) {
        int4   sa = *(const int4*)&src[e0 + i8];
        int4   sb = *(const int4*)&src[e0 + i8 + 4];
        int4   da = *(const int4*)&dst[e0 + i8];
        int4   db = *(const int4*)&dst[e0 + i8 + 4];
        float4 wa = *(const float4*)&ew[e0 + i8];
        float4 wb = *(const float4*)&ew[e0 + i8 + 4];
        int ss[8] = {sa.x, sa.y, sa.z, sa.w, sb.x, sb.y, sb.z, sb.w};
        int ds[8] = {da.x, da.y, da.z, da.w, db.x, db.y, db.z, db.w};
        float wv[8] = {wa.x, wa.y, wa.z, wa.w, wb.x, wb.y, wb.z, wb.w};
#pragma unroll
        for (int k = 0; k < 8; ++k) {
            b[k]  = ds[k] >> BSH;
            w0[k] = ss[k] | ((ds[k] & (BSZ - 1)) << 17);
            w1[k] = __float_as_int(wv[k]);
            lr[k] = atomicAdd(&hist[b[k]], 1);
        }
    } else {
#pragma unroll
        for (int k = 0; k < 8; ++k) {
            int idx = i8 + k;
            if (idx < cnt) {
                int d = dst[e0 + idx];
                b[k]  = d >> BSH;
                w0[k] = src[e0 + idx] | ((d & (BSZ - 1)) << 17);
                w1[k] = __float_as_int(ew[e0 + idx]);
                lr[k] = atomicAdd(&hist[b[k]], 1);
            }
        }
    }
    __syncthreads();
    int hv = hist[t];
    // wave-level shfl scan (2 barriers instead of 18)
    int lane = t & 63, wv8 = t >> 6;
    int s = hv;
#pragma unroll
    for (int off = 1; off < 64; off <<= 1) {
        int u = __shfl_up(s, off, 64);
        if (lane >= off) s += u;
    }
    if (lane == 63) wsum[wv8] = s;
    __syncthreads();
    int woff = 0;
#pragma unroll
    for (int w = 0; w < 8; ++w) { int x = wsum[w]; if (w < wv8) woff += x; }
    int excl = s + woff - hv;
    lbase[t] = excl;
    if (t < nbuck && hv > 0) gbase[t] = atomicAdd(&ccur[t], hv);
    __syncthreads();
#pragma unroll
    for (int k = 0; k < 8; ++k) {
        int idx = i8 + k;
        if (idx < cnt) {
            int slot = lbase[b[k]] + lr[k];
            w0s[slot] = w0[k];
            w1s[slot] = w1[k];
            bids[slot] = (unsigned char)b[k];
        }
    }
    __syncthreads();
    for (int i = t; i < cnt; i += 512) {
        int bb = bids[i];
        int pos = gbase[bb] + (i - lbase[bb]);
        pairs2[pos] = make_int2(w0s[i], w1s[i]);
    }
}

// fused pass 2, de-staged: two global passes over the bucket (L2-resident, 80KB).
// pass A: per-node counts + degree sums. pass B: fresh-rank scatter to separate
// fastU table. adaptive pad 16/32(+ext). LDS only 8KB -> high occupancy.
__global__ __launch_bounds__(512) void sort2(const int2* __restrict__ pairs2,
                                             unsigned int* __restrict__ fastU,
                                             const int* __restrict__ ccur,
                                             int2* __restrict__ extRng,
                                             unsigned int* __restrict__ extU,
                                             int* __restrict__ gext,
                                             float* __restrict__ dis,
                                             int N, int nbuck) {
    __shared__ int cnt[512];
    __shared__ float sdeg[512];
    __shared__ int cur[512];
    __shared__ int ebase[512];
    int b = blockIdx.x;
    int t = threadIdx.x;
    int baseR = b * CAPR;          // raw int2 units
    int baseF = b * FASTU;         // fast-table uint units
    int cntb = min(ccur[b] - baseR, CAPR);
    cnt[t] = 0;
    sdeg[t] = 0.0f;
    cur[t] = 0;
    __syncthreads();
    for (int i = t; i < cntb; i += 512) {
        int2 p = pairs2[baseR + i];
        int dl = (p.x >> 17) & (BSZ - 1);
        atomicAdd(&cnt[dl], 1);
        atomicAdd(&sdeg[dl], __int_as_float(p.y));
    }
    __syncthreads();
    int node = (b << BSH) + t;
    int cntv = cnt[t];
    int tot  = cntv + 1;                       // +1 self-edge
    int pc   = (tot <= 16) ? 16 : ((tot + 31) & ~31);
    int extLen = (pc > 32) ? (pc - 32) : 0;
    int extBase = 0;
    if (node < N && extLen > 0) extBase = atomicAdd(gext, extLen);  // rare
    float dloc = rsqrtf(sdeg[t] + 1.0f);
    __syncthreads();
    sdeg[t]  = dloc;               // bucket-local dis
    ebase[t] = extBase;
    if (node < N) {
        int flag = (pc == 16) ? (1 << 30) : 0;
        extRng[node] = make_int2(extBase | flag, extBase + extLen);
        dis[node]    = dloc;
    }
    // zero-fill this bucket's fast region (coalesced)
    for (int i = t; i < FASTU; i += 512) fastU[baseF + i] = 0u;
    __syncthreads();
    for (int i = t; i < cntb; i += 512) {
        int2 p = pairs2[baseR + i];
        int dl = (p.x >> 17) & (BSZ - 1);
        int s  = p.x & 0x1FFFF;
        int rank = atomicAdd(&cur[dl], 1);     // fresh ranks (uniqueness suffices)
        float w = __int_as_float(p.y) * sdeg[dl];   // ew * dis[dst]
        unsigned int h = (unsigned int)__half_as_ushort(__float2half_rn(w));
        unsigned int packed = ((unsigned int)s << 15) | ((h + 1u) >> 1);
        if (rank < 32) fastU[baseF + dl * 32 + rank] = packed;
        else           extU[ebase[dl] + rank - 32]   = packed;
    }
    __syncthreads();
    if (node < N) {
        unsigned int h = (unsigned int)__half_as_ushort(__float2half_rn(dloc));
        unsigned int selfp = ((unsigned int)node << 15) | ((h + 1u) >> 1);
        if (cntv < 32) fastU[baseF + t * 32 + cntv] = selfp;
        else           extU[extBase + cntv - 32]    = selfp;
        for (int i = cntv + 1 - 32; i < extLen; ++i) extU[extBase + i] = 0u;
    }
}

// Hb = dis * (X @ W) -> fp16; X is fp32 (layer 1) or fp16 (layer 2)
template<int HIN>
__global__ __launch_bounds__(256) void gemm64h(const void* __restrict__ Xv,
                                               const float* __restrict__ W,
                                               const float* __restrict__ dis,
                                               __half* __restrict__ Hb, int n) {
    __shared__ float Ws[64 * 64];
    __shared__ float Xs[16 * 64];
    for (int t = threadIdx.x; t < 64 * 64; t += 256) Ws[t] = W[t];
    int row0 = blockIdx.x * 16;
    for (int t = threadIdx.x; t < 16 * 64; t += 256) {
        int r = row0 + (t >> 6);
        float v = 0.0f;
        if (r < n) {
            if constexpr (HIN) v = __half2float(((const __half*)Xv)[r * 64 + (t & 63)]);
            else               v = ((const float*)Xv)[r * 64 + (t & 63)];
        }
        Xs[t] = v;
    }
    __syncthreads();
    int r  = threadIdx.x >> 4;
    int jc = (threadIdx.x & 15) * 4;
    float4 acc = make_float4(0.f, 0.f, 0.f, 0.f);
#pragma unroll
    for (int k = 0; k < 64; ++k) {
        float xv = Xs[r * 64 + k];
        float4 w = *(const float4*)&Ws[k * 64 + jc];
        acc.x += xv * w.x; acc.y += xv * w.y; acc.z += xv * w.z; acc.w += xv * w.w;
    }
    int rr = row0 + r;
    if (rr < n) {
        float ds = dis[rr];
        ushort4 pk;
        pk.x = __half_as_ushort(__float2half(ds * acc.x));
        pk.y = __half_as_ushort(__float2half(ds * acc.y));
        pk.z = __half_as_ushort(__float2half(ds * acc.z));
        pk.w = __half_as_ushort(__float2half(ds * acc.w));
        *(ushort4*)&Hb[rr * 64 + jc] = pk;
    }
}

// accumulate one 32-slot ext group (fp16 packed, 4 independent row gathers)
__device__ __forceinline__ void acc_group(unsigned int pv, int g, int fl,
                                          const __half* __restrict__ Hb,
                                          __half2 a0[4], __half2 a1[4],
                                          __half2 a2[4], __half2 a3[4]) {
    unsigned int q0 = __shfl(pv, g, 64);
    unsigned int q1 = __shfl(pv, g + 8, 64);
    unsigned int q2 = __shfl(pv, g + 16, 64);
    unsigned int q3 = __shfl(pv, g + 24, 64);
    uint4 r0 = *(const uint4*)(Hb + (size_t)(q0 >> 15) * 64 + fl);
    uint4 r1 = *(const uint4*)(Hb + (size_t)(q1 >> 15) * 64 + fl);
    uint4 r2 = *(const uint4*)(Hb + (size_t)(q2 >> 15) * 64 + fl);
    uint4 r3 = *(const uint4*)(Hb + (size_t)(q3 >> 15) * 64 + fl);
    __half2 w0 = __half2half2(__ushort_as_half((unsigned short)((q0 & 0x7FFFu) << 1)));
    __half2 w1 = __half2half2(__ushort_as_half((unsigned short)((q1 & 0x7FFFu) << 1)));
    __half2 w2 = __half2half2(__ushort_as_half((unsigned short)((q2 & 0x7FFFu) << 1)));
    __half2 w3 = __half2half2(__ushort_as_half((unsigned short)((q3 & 0x7FFFu) << 1)));
    const __half2* h0 = (const __half2*)&r0;
    const __half2* h1 = (const __half2*)&r1;
    const __half2* h2 = (const __half2*)&r2;
    const __half2* h3 = (const __half2*)&r3;
#pragma unroll
    for (int k = 0; k < 4; ++k) {
        a0[k] = __hfma2(w0, h0[k], a0[k]);
        a1[k] = __hfma2(w1, h1[k], a1[k]);
        a2[k] = __hfma2(w2, h2[k], a2[k]);
        a3[k] = __hfma2(w3, h3[k], a3[k]);
    }
}

// one wave per node; fixed fast slots (no rng indirection); adaptive 16/32 pad
// (wave-uniform skip of rows q2/q3 for small nodes); ext tail rare
template<int HOUT>
__global__ __launch_bounds__(256) void gather64(const unsigned int* __restrict__ fastU,
                                                const unsigned int* __restrict__ extU,
                                                const int2* __restrict__ extRng,
                                                const __half* __restrict__ Hb,
                                                void* __restrict__ OUTv, int N) {
    int node = blockIdx.x * 4 + (threadIdx.x >> 6);
    if (node >= N) return;
    int lane = threadIdx.x & 63;
    int g    = lane >> 3;          // edge sub-slot 0..7
    int fl   = (lane & 7) * 8;     // features fl..fl+7
    int l31  = lane & 31;
    int fbase = (node >> BSH) * FASTU + (node & (BSZ - 1)) * 32;
    unsigned int pv = fastU[fbase + l31];
    int2 er = extRng[node];        // independent load, off critical path
    bool small = (er.x & (1 << 30)) != 0;
    int eb = er.x & 0x3FFFFFFF;
    __half2 z = __float2half2_rn(0.0f);
    __half2 a0[4] = {z, z, z, z};
    __half2 a1[4] = {z, z, z, z};
    __half2 a2[4] = {z, z, z, z};
    __half2 a3[4] = {z, z, z, z};
    {
        unsigned int q0 = __shfl(pv, g, 64);
        unsigned int q1 = __shfl(pv, g + 8, 64);
        unsigned int q2 = __shfl(pv, g + 16, 64);
        unsigned int q3 = __shfl(pv, g + 24, 64);
        uint4 r0 = *(const uint4*)(Hb + (size_t)(q0 >> 15) * 64 + fl);
        uint4 r1 = *(const uint4*)(Hb + (size_t)(q1 >> 15) * 64 + fl);
        uint4 r2, r3;
        if (!small) {
            r2 = *(const uint4*)(Hb + (size_t)(q2 >> 15) * 64 + fl);
            r3 = *(const uint4*)(Hb + (size_t)(q3 >> 15) * 64 + fl);
        }
        __half2 w0 = __half2half2(__ushort_as_half((unsigned short)((q0 & 0x7FFFu) << 1)));
        __half2 w1 = __half2half2(__ushort_as_half((unsigned short)((q1 & 0x7FFFu) << 1)));
        const __half2* h0 = (const __half2*)&r0;
        const __half2* h1 = (const __half2*)&r1;
#pragma unroll
        for (int k = 0; k < 4; ++k) {
            a0[k] = __hfma2(w0, h0[k], a0[k]);
            a1[k] = __hfma2(w1, h1[k], a1[k]);
        }
        if (!small) {
            __half2 w2 = __half2half2(__ushort_as_half((unsigned short)((q2 & 0x7FFFu) << 1)));
            __half2 w3 = __half2half2(__ushort_as_half((unsigned short)((q3 & 0x7FFFu) << 1)));
            const __half2* h2 = (const __half2*)&r2;
            const __half2* h3 = (const __half2*)&r3;
#pragma unroll
            for (int k = 0; k < 4; ++k) {
                a2[k] = __hfma2(w2, h2[k], a2[k]);
                a3[k] = __hfma2(w3, h3[k], a3[k]);
            }
        }
    }
    for (int e = eb; e < er.y; e += 32)       // rare overflow tail
        acc_group(extU[e + l31], g, fl, Hb, a0, a1, a2, a3);
    __half2 a[4];
#pragma unroll
    for (int k = 0; k < 4; ++k)
        a[k] = __hadd2(__hadd2(a0[k], a1[k]), __hadd2(a2[k], a3[k]));
    // fp16 butterfly across edge sub-slots (flip lane bits 3,4,5)
#pragma unroll
    for (int m = 8; m < 64; m <<= 1) {
#pragma unroll
        for (int k = 0; k < 4; ++k) {
            unsigned u = __shfl_xor(*(unsigned*)&a[k], m, 64);
            a[k] = __hadd2(a[k], *(__half2*)&u);
        }
    }
    // lanes g=0 write features fl..fl+3, g=1 write fl+4..fl+7
    if (g < 2) {
        int o = g * 2;
        float2 f0 = __half22float2(a[o]);
        float2 f1 = __half22float2(a[o + 1]);
        float rx = fmaxf(f0.x, 0.0f), ry = fmaxf(f0.y, 0.0f);
        float rz = fmaxf(f1.x, 0.0f), rw = fmaxf(f1.y, 0.0f);
        if constexpr (HOUT) {
            ushort4 pk;
            pk.x = __half_as_ushort(__float2half(rx));
            pk.y = __half_as_ushort(__float2half(ry));
            pk.z = __half_as_ushort(__float2half(rz));
            pk.w = __half_as_ushort(__float2half(rw));
            *(ushort4*)&((__half*)OUTv)[node * 64 + fl + g * 4] = pk;
        } else {
            float4 vv = make_float4(rx, ry, rz, rw);
            *(float4*)&((float*)OUTv)[node * 64 + fl + g * 4] = vv;
        }
    }
}

extern "C" void kernel_launch(void* const* d_in, const int* in_sizes, int n_in,
                              void* d_out, int out_size, void* d_ws, size_t ws_size,
                              hipStream_t stream) {
    const float* x  = (const float*)d_in[0];
    const int*   ei = (const int*)d_in[1];   // [2, E] int32
    const float* ew = (const float*)d_in[2];
    const float* W0 = (const float*)d_in[3];
    const float* W1 = (const float*)d_in[4];
    float* out = (float*)d_out;

    const int N = in_sizes[0] / D;           // 100000
    const int E = in_sizes[2];               // 1600000
    const int* src = ei;
    const int* dst = ei + E;

    const int nbuck = (N + BSZ - 1) >> BSH;  // 196
    const int Na = (N + 1 + 255) & ~255;

    // layout (ints): dis[Na] | extRng[2*Na] | ccur[1024] |
    //                pairs2 raw [nbuck*CAPR int2] (x1h aliases after sort2) |
    //                fastU [nbuck*FASTU uints] | Hb[64N halves] | extU[262144]
    float* dis     = (float*)d_ws;
    int2*  extRng  = (int2*)((int*)d_ws + Na);
    int*   ccur    = (int*)d_ws + 3 * Na;
    int2*  pairs2  = (int2*)((int*)d_ws + 3 * Na + 1024);
    unsigned int* fastU = (unsigned int*)(pairs2 + (size_t)nbuck * CAPR);
    __half* Hb     = (__half*)(fastU + (size_t)nbuck * FASTU);
    unsigned int* extU = (unsigned int*)(Hb + (size_t)N * D);
    __half* x1h    = (__half*)pairs2;        // aliases raw (dead after sort2)

    const int nb1 = (E + PB - 1) / PB;       // 391

    // --- build node-sorted, norm-folded, packed, fixed-slot edge table + dis ---
    initcur<<<1, 256, 0, stream>>>(ccur, nbuck);
    bucket1<<<nb1, 512, 0, stream>>>(src, dst, ew, ccur, pairs2, E, nbuck);
    sort2<<<nbuck, 512, 0, stream>>>(pairs2, fastU, ccur, extRng, extU,
                                     ccur + 255, dis, N, nbuck);

    const int gemm_grid   = (N + 15) / 16;
    const int gather_grid = (N + 3) / 4;     // 1 node per wave (r14 shape)

    // --- layer 1: fp16 intermediate x1h ---
    gemm64h<0><<<gemm_grid, 256, 0, stream>>>(x, W0, dis, Hb, N);
    gather64<1><<<gather_grid, 256, 0, stream>>>(fastU, extU, extRng, Hb, x1h, N);

    // --- layer 2: fp32 output ---
    gemm64h<1><<<gemm_grid, 256, 0, stream>>>(x1h, W1, dis, Hb, N);
    gather64<0><<<gather_grid, 256, 0, stream>>>(fastU, extU, extRng, Hb, out, N);
}

// Round 18
// 188.267 us; speedup vs baseline: 1.0123x; 1.0039x over previous
//
#include <hip/hip_runtime.h>
#include <hip/hip_fp16.h>

#define D 64
#define BSH 9                   // 512 nodes per coarse bucket
#define BSZ (1 << BSH)
#define PB 4096                 // edges per pass-1 block (512 thr x 8)
#define CAPR 10240              // per-bucket raw capacity (int2 units; ~+23 sigma)
#define FASTU (BSZ * 32)        // 16384 uints of fast slots per bucket

// init per-bucket cursors to raw region bases (int2 units); ccur[255] = ext counter
__global__ __launch_bounds__(256) void initcur(int* __restrict__ ccur, int nbuck) {
    int t = threadIdx.x;
    if (t < nbuck) ccur[t] = t * CAPR;
    if (t == 255) ccur[255] = 0;
}

// pass 1: block-local counting sort into coarse buckets; coalesced run writes.
// raw edge: x = src | (dst&511)<<17 ; y = bits(ew)
__global__ __launch_bounds__(512) void bucket1(const int* __restrict__ src,
                                               const int* __restrict__ dst,
                                               const float* __restrict__ ew,
                                               int* __restrict__ ccur,
                                               int2* __restrict__ pairs2,
                                               int E, int nbuck) {
    __shared__ int hist[512];
    __shared__ int lbase[512];
    __shared__ int gbase[512];
    __shared__ int wsum[8];
    __shared__ int w0s[PB];
    __shared__ int w1s[PB];
    __shared__ unsigned char bids[PB];
    int t = threadIdx.x;
    hist[t] = 0;
    __syncthreads();
    int e0 = blockIdx.x * PB;
    int cnt = min(PB, E - e0);
    int b[8], lr[8], w0[8], w1[8];
    int i8 = t * 8;
    bool full8 = (i8 + 8 <= cnt);
    if (full8) {
        int4   sa = *(const int4*)&src[e0 + i8];
        int4   sb = *(const int4*)&src[e0 + i8 + 4];
        int4   da = *(const int4*)&dst[e0 + i8];
        int4   db = *(const int4*)&dst[e0 + i8 + 4];
        float4 wa = *(const float4*)&ew[e0 + i8];
        float4 wb = *(const float4*)&ew[e0 + i8 + 4];
        int ss[8] = {sa.x, sa.y, sa.z, sa.w, sb.x, sb.y, sb.z, sb.w};
        int ds[8] = {da.x, da.y, da.z, da.w, db.x, db.y, db.z, db.w};
        float wv[8] = {wa.x, wa.y, wa.z, wa.w, wb.x, wb.y, wb.z, wb.w};
#pragma unroll
        for (int k = 0; k < 8; ++k) {
            b[k]  = ds[k] >> BSH;
            w0[k] = ss[k] | ((ds[k] & (BSZ - 1)) << 17);
            w1[k] = __float_as_int(wv[k]);
            lr[k] = atomicAdd(&hist[b[k]], 1);
        }
    } else {
#pragma unroll
        for (int k = 0; k < 8; ++k) {
            int idx = i8 + k;
            if (idx < cnt) {
                int d = dst[e0 + idx];
                b[k]  = d >> BSH;
                w0[k] = src[e0 + idx] | ((d & (BSZ - 1)) << 17);
                w1[k] = __float_as_int(ew[e0 + idx]);
                lr[k] = atomicAdd(&hist[b[k]], 1);
            }
        }
    }
    __syncthreads();
    int hv = hist[t];
    // wave-level shfl scan (2 barriers instead of 18)
    int lane = t & 63, wv8 = t >> 6;
    int s = hv;
#pragma unroll
    for (int off = 1; off < 64; off <<= 1) {
        int u = __shfl_up(s, off, 64);
        if (lane >= off) s += u;
    }
    if (lane == 63) wsum[wv8] = s;
    __syncthreads();
    int woff = 0;
#pragma unroll
    for (int w = 0; w < 8; ++w) { int x = wsum[w]; if (w < wv8) woff += x; }
    int excl = s + woff - hv;
    lbase[t] = excl;
    if (t < nbuck && hv > 0) gbase[t] = atomicAdd(&ccur[t], hv);
    __syncthreads();
#pragma unroll
    for (int k = 0; k < 8; ++k) {
        int idx = i8 + k;
        if (idx < cnt) {
            int slot = lbase[b[k]] + lr[k];
            w0s[slot] = w0[k];
            w1s[slot] = w1[k];
            bids[slot] = (unsigned char)b[k];
        }
    }
    __syncthreads();
    for (int i = t; i < cnt; i += 512) {
        int bb = bids[i];
        int pos = gbase[bb] + (i - lbase[bb]);
        pairs2[pos] = make_int2(w0s[i], w1s[i]);
    }
}

// fused pass 2, de-staged: two global passes over the bucket (L2-resident, 80KB).
// pass A: per-node counts + degree sums. pass B: fresh-rank scatter to fastU.
// three-tier pad 16/24/32(+ext); tier code in bits 29-30 of extRng.x.
__global__ __launch_bounds__(512) void sort2(const int2* __restrict__ pairs2,
                                             unsigned int* __restrict__ fastU,
                                             const int* __restrict__ ccur,
                                             int2* __restrict__ extRng,
                                             unsigned int* __restrict__ extU,
                                             int* __restrict__ gext,
                                             float* __restrict__ dis,
                                             int N, int nbuck) {
    __shared__ int cnt[512];
    __shared__ float sdeg[512];
    __shared__ int cur[512];
    __shared__ int ebase[512];
    int b = blockIdx.x;
    int t = threadIdx.x;
    int baseR = b * CAPR;          // raw int2 units
    int baseF = b * FASTU;         // fast-table uint units
    int cntb = min(ccur[b] - baseR, CAPR);
    cnt[t] = 0;
    sdeg[t] = 0.0f;
    cur[t] = 0;
    __syncthreads();
    for (int i = t; i < cntb; i += 512) {
        int2 p = pairs2[baseR + i];
        int dl = (p.x >> 17) & (BSZ - 1);
        atomicAdd(&cnt[dl], 1);
        atomicAdd(&sdeg[dl], __int_as_float(p.y));
    }
    __syncthreads();
    int node = (b << BSH) + t;
    int cntv = cnt[t];
    int tot  = cntv + 1;                       // +1 self-edge
    int pc;
    if (tot <= 16)      pc = 16;
    else if (tot <= 24) pc = 24;
    else                pc = (tot + 31) & ~31;
    int code = (pc == 16) ? 0 : (pc == 24) ? 1 : 2;
    int extLen = (pc > 32) ? (pc - 32) : 0;
    int extBase = 0;
    if (node < N && extLen > 0) extBase = atomicAdd(gext, extLen);  // rare
    float dloc = rsqrtf(sdeg[t] + 1.0f);
    __syncthreads();
    sdeg[t]  = dloc;               // bucket-local dis
    ebase[t] = extBase;
    if (node < N) {
        extRng[node] = make_int2(extBase | (code << 29), extBase + extLen);
        dis[node]    = dloc;
    }
    // zero-fill this bucket's fast region (coalesced)
    for (int i = t; i < FASTU; i += 512) fastU[baseF + i] = 0u;
    __syncthreads();
    for (int i = t; i < cntb; i += 512) {
        int2 p = pairs2[baseR + i];
        int dl = (p.x >> 17) & (BSZ - 1);
        int s  = p.x & 0x1FFFF;
        int rank = atomicAdd(&cur[dl], 1);     // fresh ranks (uniqueness suffices)
        float w = __int_as_float(p.y) * sdeg[dl];   // ew * dis[dst]
        unsigned int h = (unsigned int)__half_as_ushort(__float2half_rn(w));
        unsigned int packed = ((unsigned int)s << 15) | ((h + 1u) >> 1);
        if (rank < 32) fastU[baseF + dl * 32 + rank] = packed;
        else           extU[ebase[dl] + rank - 32]   = packed;
    }
    __syncthreads();
    if (node < N) {
        unsigned int h = (unsigned int)__half_as_ushort(__float2half_rn(dloc));
        unsigned int selfp = ((unsigned int)node << 15) | ((h + 1u) >> 1);
        if (cntv < 32) fastU[baseF + t * 32 + cntv] = selfp;
        else           extU[extBase + cntv - 32]    = selfp;
        for (int i = cntv + 1 - 32; i < extLen; ++i) extU[extBase + i] = 0u;
    }
}

// Hb = dis * (X @ W) -> fp16; X is fp32 (layer 1) or fp16 (layer 2)
template<int HIN>
__global__ __launch_bounds__(256) void gemm64h(const void* __restrict__ Xv,
                                               const float* __restrict__ W,
                                               const float* __restrict__ dis,
                                               __half* __restrict__ Hb, int n) {
    __shared__ float Ws[64 * 64];
    __shared__ float Xs[16 * 64];
    for (int t = threadIdx.x; t < 64 * 64; t += 256) Ws[t] = W[t];
    int row0 = blockIdx.x * 16;
    for (int t = threadIdx.x; t < 16 * 64; t += 256) {
        int r = row0 + (t >> 6);
        float v = 0.0f;
        if (r < n) {
            if constexpr (HIN) v = __half2float(((const __half*)Xv)[r * 64 + (t & 63)]);
            else               v = ((const float*)Xv)[r * 64 + (t & 63)];
        }
        Xs[t] = v;
    }
    __syncthreads();
    int r  = threadIdx.x >> 4;
    int jc = (threadIdx.x & 15) * 4;
    float4 acc = make_float4(0.f, 0.f, 0.f, 0.f);
#pragma unroll
    for (int k = 0; k < 64; ++k) {
        float xv = Xs[r * 64 + k];
        float4 w = *(const float4*)&Ws[k * 64 + jc];
        acc.x += xv * w.x; acc.y += xv * w.y; acc.z += xv * w.z; acc.w += xv * w.w;
    }
    int rr = row0 + r;
    if (rr < n) {
        float ds = dis[rr];
        ushort4 pk;
        pk.x = __half_as_ushort(__float2half(ds * acc.x));
        pk.y = __half_as_ushort(__float2half(ds * acc.y));
        pk.z = __half_as_ushort(__float2half(ds * acc.z));
        pk.w = __half_as_ushort(__float2half(ds * acc.w));
        *(ushort4*)&Hb[rr * 64 + jc] = pk;
    }
}

// accumulate one 32-slot ext group (fp16 packed, 4 independent row gathers)
__device__ __forceinline__ void acc_group(unsigned int pv, int g, int fl,
                                          const __half* __restrict__ Hb,
                                          __half2 a0[4], __half2 a1[4],
                                          __half2 a2[4], __half2 a3[4]) {
    unsigned int q0 = __shfl(pv, g, 64);
    unsigned int q1 = __shfl(pv, g + 8, 64);
    unsigned int q2 = __shfl(pv, g + 16, 64);
    unsigned int q3 = __shfl(pv, g + 24, 64);
    uint4 r0 = *(const uint4*)(Hb + (size_t)(q0 >> 15) * 64 + fl);
    uint4 r1 = *(const uint4*)(Hb + (size_t)(q1 >> 15) * 64 + fl);
    uint4 r2 = *(const uint4*)(Hb + (size_t)(q2 >> 15) * 64 + fl);
    uint4 r3 = *(const uint4*)(Hb + (size_t)(q3 >> 15) * 64 + fl);
    __half2 w0 = __half2half2(__ushort_as_half((unsigned short)((q0 & 0x7FFFu) << 1)));
    __half2 w1 = __half2half2(__ushort_as_half((unsigned short)((q1 & 0x7FFFu) << 1)));
    __half2 w2 = __half2half2(__ushort_as_half((unsigned short)((q2 & 0x7FFFu) << 1)));
    __half2 w3 = __half2half2(__ushort_as_half((unsigned short)((q3 & 0x7FFFu) << 1)));
    const __half2* h0 = (const __half2*)&r0;
    const __half2* h1 = (const __half2*)&r1;
    const __half2* h2 = (const __half2*)&r2;
    const __half2* h3 = (const __half2*)&r3;
#pragma unroll
    for (int k = 0; k < 4; ++k) {
        a0[k] = __hfma2(w0, h0[k], a0[k]);
        a1[k] = __hfma2(w1, h1[k], a1[k]);
        a2[k] = __hfma2(w2, h2[k], a2[k]);
        a3[k] = __hfma2(w3, h3[k], a3[k]);
    }
}

// one wave per node; fixed fast slots; three-tier 16/24/32 pad (wave-uniform
// skip of rows q2 and/or q3); ext tail rare
template<int HOUT>
__global__ __launch_bounds__(256) void gather64(const unsigned int* __restrict__ fastU,
                                                const unsigned int* __restrict__ extU,
                                                const int2* __restrict__ extRng,
                                                const __half* __restrict__ Hb,
                                                void* __restrict__ OUTv, int N) {
    int node = blockIdx.x * 4 + (threadIdx.x >> 6);
    if (node >= N) return;
    int lane = threadIdx.x & 63;
    int g    = lane >> 3;          // edge sub-slot 0..7
    int fl   = (lane & 7) * 8;     // features fl..fl+7
    int l31  = lane & 31;
    int fbase = (node >> BSH) * FASTU + (node & (BSZ - 1)) * 32;
    unsigned int pv = fastU[fbase + l31];
    int2 er = extRng[node];        // independent load, off critical path
    int code = ((unsigned int)er.x >> 29) & 3;   // 0:16, 1:24, 2:32(+ext)
    int eb = er.x & 0x1FFFFFFF;
    __half2 z = __float2half2_rn(0.0f);
    __half2 a0[4] = {z, z, z, z};
    __half2 a1[4] = {z, z, z, z};
    __half2 a2[4] = {z, z, z, z};
    __half2 a3[4] = {z, z, z, z};
    {
        unsigned int q0 = __shfl(pv, g, 64);
        unsigned int q1 = __shfl(pv, g + 8, 64);
        unsigned int q2 = __shfl(pv, g + 16, 64);
        unsigned int q3 = __shfl(pv, g + 24, 64);
        uint4 r0 = *(const uint4*)(Hb + (size_t)(q0 >> 15) * 64 + fl);
        uint4 r1 = *(const uint4*)(Hb + (size_t)(q1 >> 15) * 64 + fl);
        uint4 r2, r3;
        if (code >= 1) r2 = *(const uint4*)(Hb + (size_t)(q2 >> 15) * 64 + fl);
        if (code >= 2) r3 = *(const uint4*)(Hb + (size_t)(q3 >> 15) * 64 + fl);
        __half2 w0 = __half2half2(__ushort_as_half((unsigned short)((q0 & 0x7FFFu) << 1)));
        __half2 w1 = __half2half2(__ushort_as_half((unsigned short)((q1 & 0x7FFFu) << 1)));
        const __half2* h0 = (const __half2*)&r0;
        const __half2* h1 = (const __half2*)&r1;
#pragma unroll
        for (int k = 0; k < 4; ++k) {
            a0[k] = __hfma2(w0, h0[k], a0[k]);
            a1[k] = __hfma2(w1, h1[k], a1[k]);
        }
        if (code >= 1) {
            __half2 w2 = __half2half2(__ushort_as_half((unsigned short)((q2 & 0x7FFFu) << 1)));
            const __half2* h2 = (const __half2*)&r2;
#pragma unroll
            for (int k = 0; k < 4; ++k) a2[k] = __hfma2(w2, h2[k], a2[k]);
        }
        if (code >= 2) {
            __half2 w3 = __half2half2(__ushort_as_half((unsigned short)((q3 & 0x7FFFu) << 1)));
            const __half2* h3 = (const __half2*)&r3;
#pragma unroll
            for (int k = 0; k < 4; ++k) a3[k] = __hfma2(w3, h3[k], a3[k]);
        }
    }
    for (int e = eb; e < er.y; e += 32)       // rare overflow tail
        acc_group(extU[e + l31], g, fl, Hb, a0, a1, a2, a3);
    __half2 a[4];
#pragma unroll
    for (int k = 0; k < 4; ++k)
        a[k] = __hadd2(__hadd2(a0[k], a1[k]), __hadd2(a2[k], a3[k]));
    // fp16 butterfly across edge sub-slots (flip lane bits 3,4,5)
#pragma unroll
    for (int m = 8; m < 64; m <<= 1) {
#pragma unroll
        for (int k = 0; k < 4; ++k) {
            unsigned u = __shfl_xor(*(unsigned*)&a[k], m, 64);
            a[k] = __hadd2(a[k], *(__half2*)&u);
        }
    }
    // lanes g=0 write features fl..fl+3, g=1 write fl+4..fl+7
    if (g < 2) {
        int o = g * 2;
        float2 f0 = __half22float2(a[o]);
        float2 f1 = __half22float2(a[o + 1]);
        float rx = fmaxf(f0.x, 0.0f), ry = fmaxf(f0.y, 0.0f);
        float rz = fmaxf(f1.x, 0.0f), rw = fmaxf(f1.y, 0.0f);
        if constexpr (HOUT) {
            ushort4 pk;
            pk.x = __half_as_ushort(__float2half(rx));
            pk.y = __half_as_ushort(__float2half(ry));
            pk.z = __half_as_ushort(__float2half(rz));
            pk.w = __half_as_ushort(__float2half(rw));
            *(ushort4*)&((__half*)OUTv)[node * 64 + fl + g * 4] = pk;
        } else {
            float4 vv = make_float4(rx, ry, rz, rw);
            *(float4*)&((float*)OUTv)[node * 64 + fl + g * 4] = vv;
        }
    }
}

extern "C" void kernel_launch(void* const* d_in, const int* in_sizes, int n_in,
                              void* d_out, int out_size, void* d_ws, size_t ws_size,
                              hipStream_t stream) {
    const float* x  = (const float*)d_in[0];
    const int*   ei = (const int*)d_in[1];   // [2, E] int32
    const float* ew = (const float*)d_in[2];
    const float* W0 = (const float*)d_in[3];
    const float* W1 = (const float*)d_in[4];
    float* out = (float*)d_out;

    const int N = in_sizes[0] / D;           // 100000
    const int E = in_sizes[2];               // 1600000
    const int* src = ei;
    const int* dst = ei + E;

    const int nbuck = (N + BSZ - 1) >> BSH;  // 196
    const int Na = (N + 1 + 255) & ~255;

    // layout (ints): dis[Na] | extRng[2*Na] | ccur[1024] |
    //                pairs2 raw [nbuck*CAPR int2] (x1h aliases after sort2) |
    //                fastU [nbuck*FASTU uints] | Hb[64N halves] | extU[262144]
    float* dis     = (float*)d_ws;
    int2*  extRng  = (int2*)((int*)d_ws + Na);
    int*   ccur    = (int*)d_ws + 3 * Na;
    int2*  pairs2  = (int2*)((int*)d_ws + 3 * Na + 1024);
    unsigned int* fastU = (unsigned int*)(pairs2 + (size_t)nbuck * CAPR);
    __half* Hb     = (__half*)(fastU + (size_t)nbuck * FASTU);
    unsigned int* extU = (unsigned int*)(Hb + (size_t)N * D);
    __half* x1h    = (__half*)pairs2;        // aliases raw (dead after sort2)

    const int nb1 = (E + PB - 1) / PB;       // 391

    // --- build node-sorted, norm-folded, packed, fixed-slot edge table + dis ---
    initcur<<<1, 256, 0, stream>>>(ccur, nbuck);
    bucket1<<<nb1, 512, 0, stream>>>(src, dst, ew, ccur, pairs2, E, nbuck);
    sort2<<<nbuck, 512, 0, stream>>>(pairs2, fastU, ccur, extRng, extU,
                                     ccur + 255, dis, N, nbuck);

    const int gemm_grid   = (N + 15) / 16;
    const int gather_grid = (N + 3) / 4;

    // --- layer 1: fp16 intermediate x1h ---
    gemm64h<0><<<gemm_grid, 256, 0, stream>>>(x, W0, dis, Hb, N);
    gather64<1><<<gather_grid, 256, 0, stream>>>(fastU, extU, extRng, Hb, x1h, N);

    // --- layer 2: fp32 output ---
    gemm64h<1><<<gemm_grid, 256, 0, stream>>>(x1h, W1, dis, Hb, N);
    gather64<0><<<gather_grid, 256, 0, stream>>>(fastU, extU, extRng, Hb, out, N);
}

// Round 19
// 186.830 us; speedup vs baseline: 1.0201x; 1.0077x over previous
//
#include <hip/hip_runtime.h>
#include <hip/hip_fp16.h>

#define D 64
#define BSH 9                   // 512 nodes per coarse bucket
#define BSZ (1 << BSH)
#define PB 4096                 // edges per pass-1 block (512 thr x 8)
#define CAPR 10240              // per-bucket raw capacity (int2 units; ~+23 sigma)
#define FASTU (BSZ * 32)        // 16384 uints of fast slots per bucket

// init per-bucket cursors to raw region bases (int2 units); ccur[255] = ext counter
__global__ __launch_bounds__(256) void initcur(int* __restrict__ ccur, int nbuck) {
    int t = threadIdx.x;
    if (t < nbuck) ccur[t] = t * CAPR;
    if (t == 255) ccur[255] = 0;
}

// pass 1: block-local counting sort into coarse buckets; coalesced run writes.
// raw edge: x = src | (dst&511)<<17 ; y = bits(ew)
__global__ __launch_bounds__(512) void bucket1(const int* __restrict__ src,
                                               const int* __restrict__ dst,
                                               const float* __restrict__ ew,
                                               int* __restrict__ ccur,
                                               int2* __restrict__ pairs2,
                                               int E, int nbuck) {
    __shared__ int hist[512];
    __shared__ int lbase[512];
    __shared__ int gbase[512];
    __shared__ int wsum[8];
    __shared__ int w0s[PB];
    __shared__ int w1s[PB];
    __shared__ unsigned char bids[PB];
    int t = threadIdx.x;
    hist[t] = 0;
    __syncthreads();
    int e0 = blockIdx.x * PB;
    int cnt = min(PB, E - e0);
    int b[8], lr[8], w0[8], w1[8];
    int i8 = t * 8;
    bool full8 = (i8 + 8 <= cnt);
    if (full8) {
        int4   sa = *(const int4*)&src[e0 + i8];
        int4   sb = *(const int4*)&src[e0 + i8 + 4];
        int4   da = *(const int4*)&dst[e0 + i8];
        int4   db = *(const int4*)&dst[e0 + i8 + 4];
        float4 wa = *(const float4*)&ew[e0 + i8];
        float4 wb = *(const float4*)&ew[e0 + i8 + 4];
        int ss[8] = {sa.x, sa.y, sa.z, sa.w, sb.x, sb.y, sb.z, sb.w};
        int ds[8] = {da.x, da.y, da.z, da.w, db.x, db.y, db.z, db.w};
        float wv[8] = {wa.x, wa.y, wa.z, wa.w, wb.x, wb.y, wb.z, wb.w};
#pragma unroll
        for (int k = 0; k < 8; ++k) {
            b[k]  = ds[k] >> BSH;
            w0[k] = ss[k] | ((ds[k] & (BSZ - 1)) << 17);
            w1[k] = __float_as_int(wv[k]);
            lr[k] = atomicAdd(&hist[b[k]], 1);
        }
    } else {
#pragma unroll
        for (int k = 0; k < 8; ++k) {
            int idx = i8 + k;
            if (idx < cnt) {
                int d = dst[e0 + idx];
                b[k]  = d >> BSH;
                w0[k] = src[e0 + idx] | ((d & (BSZ - 1)) << 17);
                w1[k] = __float_as_int(ew[e0 + idx]);
                lr[k] = atomicAdd(&hist[b[k]], 1);
            }
        }
    }
    __syncthreads();
    int hv = hist[t];
    // wave-level shfl scan (2 barriers instead of 18)
    int lane = t & 63, wv8 = t >> 6;
    int s = hv;
#pragma unroll
    for (int off = 1; off < 64; off <<= 1) {
        int u = __shfl_up(s, off, 64);
        if (lane >= off) s += u;
    }
    if (lane == 63) wsum[wv8] = s;
    __syncthreads();
    int woff = 0;
#pragma unroll
    for (int w = 0; w < 8; ++w) { int x = wsum[w]; if (w < wv8) woff += x; }
    int excl = s + woff - hv;
    lbase[t] = excl;
    if (t < nbuck && hv > 0) gbase[t] = atomicAdd(&ccur[t], hv);
    __syncthreads();
#pragma unroll
    for (int k = 0; k < 8; ++k) {
        int idx = i8 + k;
        if (idx < cnt) {
            int slot = lbase[b[k]] + lr[k];
            w0s[slot] = w0[k];
            w1s[slot] = w1[k];
            bids[slot] = (unsigned char)b[k];
        }
    }
    __syncthreads();
    for (int i = t; i < cnt; i += 512) {
        int bb = bids[i];
        int pos = gbase[bb] + (i - lbase[bb]);
        pairs2[pos] = make_int2(w0s[i], w1s[i]);
    }
}

// fused pass 2, de-staged, NO zero-fill: pad slots are masked logically in
// gather via tot (packed in extRng.y). pass A: counts+deg. pass B: fresh-rank
// scatter to fastU. tiers 16/24/32(+ext); code in bits 29-30 of extRng.x;
// extRng.y = tot | extGroups<<16.
__global__ __launch_bounds__(512) void sort2(const int2* __restrict__ pairs2,
                                             unsigned int* __restrict__ fastU,
                                             const int* __restrict__ ccur,
                                             int2* __restrict__ extRng,
                                             unsigned int* __restrict__ extU,
                                             int* __restrict__ gext,
                                             float* __restrict__ dis,
                                             int N, int nbuck) {
    __shared__ int cnt[512];
    __shared__ float sdeg[512];
    __shared__ int cur[512];
    __shared__ int ebase[512];
    int b = blockIdx.x;
    int t = threadIdx.x;
    int baseR = b * CAPR;          // raw int2 units
    int baseF = b * FASTU;         // fast-table uint units
    int cntb = min(ccur[b] - baseR, CAPR);
    cnt[t] = 0;
    sdeg[t] = 0.0f;
    cur[t] = 0;
    __syncthreads();
    for (int i = t; i < cntb; i += 512) {
        int2 p = pairs2[baseR + i];
        int dl = (p.x >> 17) & (BSZ - 1);
        atomicAdd(&cnt[dl], 1);
        atomicAdd(&sdeg[dl], __int_as_float(p.y));
    }
    __syncthreads();
    int node = (b << BSH) + t;
    int cntv = cnt[t];
    int tot  = cntv + 1;                       // +1 self-edge
    int pc;
    if (tot <= 16)      pc = 16;
    else if (tot <= 24) pc = 24;
    else                pc = (tot + 31) & ~31;
    int code = (pc == 16) ? 0 : (pc == 24) ? 1 : 2;
    int extLen = (pc > 32) ? (pc - 32) : 0;
    int extBase = 0;
    if (node < N && extLen > 0) extBase = atomicAdd(gext, extLen);  // rare
    float dloc = rsqrtf(sdeg[t] + 1.0f);
    __syncthreads();
    sdeg[t]  = dloc;               // bucket-local dis
    ebase[t] = extBase;
    if (node < N) {
        extRng[node] = make_int2(extBase | (code << 29),
                                 tot | ((extLen >> 5) << 16));
        dis[node]    = dloc;
    }
    __syncthreads();
    for (int i = t; i < cntb; i += 512) {
        int2 p = pairs2[baseR + i];
        int dl = (p.x >> 17) & (BSZ - 1);
        int s  = p.x & 0x1FFFF;
        int rank = atomicAdd(&cur[dl], 1);     // fresh ranks (uniqueness suffices)
        float w = __int_as_float(p.y) * sdeg[dl];   // ew * dis[dst]
        unsigned int h = (unsigned int)__half_as_ushort(__float2half_rn(w));
        unsigned int packed = ((unsigned int)s << 15) | ((h + 1u) >> 1);
        if (rank < 32) fastU[baseF + dl * 32 + rank] = packed;
        else           extU[ebase[dl] + rank - 32]   = packed;
    }
    __syncthreads();
    if (node < N) {
        unsigned int h = (unsigned int)__half_as_ushort(__float2half_rn(dloc));
        unsigned int selfp = ((unsigned int)node << 15) | ((h + 1u) >> 1);
        if (cntv < 32) fastU[baseF + t * 32 + cntv] = selfp;
        else           extU[extBase + cntv - 32]    = selfp;
        for (int i = cntv + 1 - 32; i < extLen; ++i) extU[extBase + i] = 0u;
    }
}

// Hb = dis * (X @ W) -> fp16; X is fp32 (layer 1) or fp16 (layer 2)
template<int HIN>
__global__ __launch_bounds__(256) void gemm64h(const void* __restrict__ Xv,
                                               const float* __restrict__ W,
                                               const float* __restrict__ dis,
                                               __half* __restrict__ Hb, int n) {
    __shared__ float Ws[64 * 64];
    __shared__ float Xs[16 * 64];
    for (int t = threadIdx.x; t < 64 * 64; t += 256) Ws[t] = W[t];
    int row0 = blockIdx.x * 16;
    for (int t = threadIdx.x; t < 16 * 64; t += 256) {
        int r = row0 + (t >> 6);
        float v = 0.0f;
        if (r < n) {
            if constexpr (HIN) v = __half2float(((const __half*)Xv)[r * 64 + (t & 63)]);
            else               v = ((const float*)Xv)[r * 64 + (t & 63)];
        }
        Xs[t] = v;
    }
    __syncthreads();
    int r  = threadIdx.x >> 4;
    int jc = (threadIdx.x & 15) * 4;
    float4 acc = make_float4(0.f, 0.f, 0.f, 0.f);
#pragma unroll
    for (int k = 0; k < 64; ++k) {
        float xv = Xs[r * 64 + k];
        float4 w = *(const float4*)&Ws[k * 64 + jc];
        acc.x += xv * w.x; acc.y += xv * w.y; acc.z += xv * w.z; acc.w += xv * w.w;
    }
    int rr = row0 + r;
    if (rr < n) {
        float ds = dis[rr];
        ushort4 pk;
        pk.x = __half_as_ushort(__float2half(ds * acc.x));
        pk.y = __half_as_ushort(__float2half(ds * acc.y));
        pk.z = __half_as_ushort(__float2half(ds * acc.z));
        pk.w = __half_as_ushort(__float2half(ds * acc.w));
        *(ushort4*)&Hb[rr * 64 + jc] = pk;
    }
}

// accumulate one 32-slot ext group (fp16 packed, 4 independent row gathers)
__device__ __forceinline__ void acc_group(unsigned int pv, int g, int fl,
                                          const __half* __restrict__ Hb,
                                          __half2 a0[4], __half2 a1[4],
                                          __half2 a2[4], __half2 a3[4]) {
    unsigned int q0 = __shfl(pv, g, 64);
    unsigned int q1 = __shfl(pv, g + 8, 64);
    unsigned int q2 = __shfl(pv, g + 16, 64);
    unsigned int q3 = __shfl(pv, g + 24, 64);
    uint4 r0 = *(const uint4*)(Hb + (size_t)(q0 >> 15) * 64 + fl);
    uint4 r1 = *(const uint4*)(Hb + (size_t)(q1 >> 15) * 64 + fl);
    uint4 r2 = *(const uint4*)(Hb + (size_t)(q2 >> 15) * 64 + fl);
    uint4 r3 = *(const uint4*)(Hb + (size_t)(q3 >> 15) * 64 + fl);
    __half2 w0 = __half2half2(__ushort_as_half((unsigned short)((q0 & 0x7FFFu) << 1)));
    __half2 w1 = __half2half2(__ushort_as_half((unsigned short)((q1 & 0x7FFFu) << 1)));
    __half2 w2 = __half2half2(__ushort_as_half((unsigned short)((q2 & 0x7FFFu) << 1)));
    __half2 w3 = __half2half2(__ushort_as_half((unsigned short)((q3 & 0x7FFFu) << 1)));
    const __half2* h0 = (const __half2*)&r0;
    const __half2* h1 = (const __half2*)&r1;
    const __half2* h2 = (const __half2*)&r2;
    const __half2* h3 = (const __half2*)&r3;
#pragma unroll
    for (int k = 0; k < 4; ++k) {
        a0[k] = __hfma2(w0, h0[k], a0[k]);
        a1[k] = __hfma2(w1, h1[k], a1[k]);
        a2[k] = __hfma2(w2, h2[k], a2[k]);
        a3[k] = __hfma2(w3, h3[k], a3[k]);
    }
}

// one wave per node; fixed fast slots; tiers 16/24/32; pad slots masked via tot
// (q -> 0 gives src=0,w=0: identical semantics to a zeroed pad, L1-hot row 0)
template<int HOUT>
__global__ __launch_bounds__(256) void gather64(const unsigned int* __restrict__ fastU,
                                                const unsigned int* __restrict__ extU,
                                                const int2* __restrict__ extRng,
                                                const __half* __restrict__ Hb,
                                                void* __restrict__ OUTv, int N) {
    int node = blockIdx.x * 4 + (threadIdx.x >> 6);
    if (node >= N) return;
    int lane = threadIdx.x & 63;
    int g    = lane >> 3;          // edge sub-slot 0..7
    int fl   = (lane & 7) * 8;     // features fl..fl+7
    int l31  = lane & 31;
    int fbase = (node >> BSH) * FASTU + (node & (BSZ - 1)) * 32;
    unsigned int pv = fastU[fbase + l31];
    int2 er = extRng[node];        // independent load, off critical path
    int code = ((unsigned int)er.x >> 29) & 3;   // 0:16, 1:24, 2:32(+ext)
    int eb   = er.x & 0x1FFFFFFF;
    int tot  = er.y & 0xFFFF;
    int extG = ((unsigned int)er.y >> 16);
    __half2 z = __float2half2_rn(0.0f);
    __half2 a0[4] = {z, z, z, z};
    __half2 a1[4] = {z, z, z, z};
    __half2 a2[4] = {z, z, z, z};
    __half2 a3[4] = {z, z, z, z};
    {
        unsigned int q0 = __shfl(pv, g, 64);
        unsigned int q1 = __shfl(pv, g + 8, 64);
        unsigned int q2 = __shfl(pv, g + 16, 64);
        unsigned int q3 = __shfl(pv, g + 24, 64);
        q0 = (g      < tot) ? q0 : 0u;   // mask pad/garbage slots
        q1 = (g + 8  < tot) ? q1 : 0u;
        q2 = (g + 16 < tot) ? q2 : 0u;
        q3 = (g + 24 < tot) ? q3 : 0u;
        uint4 r0 = *(const uint4*)(Hb + (size_t)(q0 >> 15) * 64 + fl);
        uint4 r1 = *(const uint4*)(Hb + (size_t)(q1 >> 15) * 64 + fl);
        uint4 r2, r3;
        if (code >= 1) r2 = *(const uint4*)(Hb + (size_t)(q2 >> 15) * 64 + fl);
        if (code >= 2) r3 = *(const uint4*)(Hb + (size_t)(q3 >> 15) * 64 + fl);
        __half2 w0 = __half2half2(__ushort_as_half((unsigned short)((q0 & 0x7FFFu) << 1)));
        __half2 w1 = __half2half2(__ushort_as_half((unsigned short)((q1 & 0x7FFFu) << 1)));
        const __half2* h0 = (const __half2*)&r0;
        const __half2* h1 = (const __half2*)&r1;
#pragma unroll
        for (int k = 0; k < 4; ++k) {
            a0[k] = __hfma2(w0, h0[k], a0[k]);
            a1[k] = __hfma2(w1, h1[k], a1[k]);
        }
        if (code >= 1) {
            __half2 w2 = __half2half2(__ushort_as_half((unsigned short)((q2 & 0x7FFFu) << 1)));
            const __half2* h2 = (const __half2*)&r2;
#pragma unroll
            for (int k = 0; k < 4; ++k) a2[k] = __hfma2(w2, h2[k], a2[k]);
        }
        if (code >= 2) {
            __half2 w3 = __half2half2(__ushort_as_half((unsigned short)((q3 & 0x7FFFu) << 1)));
            const __half2* h3 = (const __half2*)&r3;
#pragma unroll
            for (int k = 0; k < 4; ++k) a3[k] = __hfma2(w3, h3[k], a3[k]);
        }
    }
    for (int eg = 0; eg < extG; ++eg)         // rare overflow tail (zero-padded)
        acc_group(extU[eb + eg * 32 + l31], g, fl, Hb, a0, a1, a2, a3);
    __half2 a[4];
#pragma unroll
    for (int k = 0; k < 4; ++k)
        a[k] = __hadd2(__hadd2(a0[k], a1[k]), __hadd2(a2[k], a3[k]));
    // fp16 butterfly across edge sub-slots (flip lane bits 3,4,5)
#pragma unroll
    for (int m = 8; m < 64; m <<= 1) {
#pragma unroll
        for (int k = 0; k < 4; ++k) {
            unsigned u = __shfl_xor(*(unsigned*)&a[k], m, 64);
            a[k] = __hadd2(a[k], *(__half2*)&u);
        }
    }
    // lanes g=0 write features fl..fl+3, g=1 write fl+4..fl+7
    if (g < 2) {
        int o = g * 2;
        float2 f0 = __half22float2(a[o]);
        float2 f1 = __half22float2(a[o + 1]);
        float rx = fmaxf(f0.x, 0.0f), ry = fmaxf(f0.y, 0.0f);
        float rz = fmaxf(f1.x, 0.0f), rw = fmaxf(f1.y, 0.0f);
        if constexpr (HOUT) {
            ushort4 pk;
            pk.x = __half_as_ushort(__float2half(rx));
            pk.y = __half_as_ushort(__float2half(ry));
            pk.z = __half_as_ushort(__float2half(rz));
            pk.w = __half_as_ushort(__float2half(rw));
            *(ushort4*)&((__half*)OUTv)[node * 64 + fl + g * 4] = pk;
        } else {
            float4 vv = make_float4(rx, ry, rz, rw);
            *(float4*)&((float*)OUTv)[node * 64 + fl + g * 4] = vv;
        }
    }
}

extern "C" void kernel_launch(void* const* d_in, const int* in_sizes, int n_in,
                              void* d_out, int out_size, void* d_ws, size_t ws_size,
                              hipStream_t stream) {
    const float* x  = (const float*)d_in[0];
    const int*   ei = (const int*)d_in[1];   // [2, E] int32
    const float* ew = (const float*)d_in[2];
    const float* W0 = (const float*)d_in[3];
    const float* W1 = (const float*)d_in[4];
    float* out = (float*)d_out;

    const int N = in_sizes[0] / D;           // 100000
    const int E = in_sizes[2];               // 1600000
    const int* src = ei;
    const int* dst = ei + E;

    const int nbuck = (N + BSZ - 1) >> BSH;  // 196
    const int Na = (N + 1 + 255) & ~255;

    // layout (ints): dis[Na] | extRng[2*Na] | ccur[1024] |
    //                pairs2 raw [nbuck*CAPR int2] (x1h aliases after sort2) |
    //                fastU [nbuck*FASTU uints] | Hb[64N halves] | extU[262144]
    float* dis     = (float*)d_ws;
    int2*  extRng  = (int2*)((int*)d_ws + Na);
    int*   ccur    = (int*)d_ws + 3 * Na;
    int2*  pairs2  = (int2*)((int*)d_ws + 3 * Na + 1024);
    unsigned int* fastU = (unsigned int*)(pairs2 + (size_t)nbuck * CAPR);
    __half* Hb     = (__half*)(fastU + (size_t)nbuck * FASTU);
    unsigned int* extU = (unsigned int*)(Hb + (size_t)N * D);
    __half* x1h    = (__half*)pairs2;        // aliases raw (dead after sort2)

    const int nb1 = (E + PB - 1) / PB;       // 391

    // --- build node-sorted, norm-folded, packed, fixed-slot edge table + dis ---
    initcur<<<1, 256, 0, stream>>>(ccur, nbuck);
    bucket1<<<nb1, 512, 0, stream>>>(src, dst, ew, ccur, pairs2, E, nbuck);
    sort2<<<nbuck, 512, 0, stream>>>(pairs2, fastU, ccur, extRng, extU,
                                     ccur + 255, dis, N, nbuck);

    const int gemm_grid   = (N + 15) / 16;
    const int gather_grid = (N + 3) / 4;

    // --- layer 1: fp16 intermediate x1h ---
    gemm64h<0><<<gemm_grid, 256, 0, stream>>>(x, W0, dis, Hb, N);
    gather64<1><<<gather_grid, 256, 0, stream>>>(fastU, extU, extRng, Hb, x1h, N);

    // --- layer 2: fp32 output ---
    gemm64h<1><<<gemm_grid, 256, 0, stream>>>(x1h, W1, dis, Hb, N);
    gather64<0><<<gather_grid, 256, 0, stream>>>(fastU, extU, extRng, Hb, out, N);
}

// Round 20
// 186.696 us; speedup vs baseline: 1.0208x; 1.0007x over previous
//
#include <hip/hip_runtime.h>
#include <hip/hip_fp16.h>

#define D 64
#define BSH 9                   // 512 nodes per coarse bucket
#define BSZ (1 << BSH)
#define PB 4096                 // edges per pass-1 block (512 thr x 8)
#define CAPR 10240              // per-bucket raw capacity (int2 units; ~+23 sigma)
#define FASTU (BSZ * 32)        // 16384 uints of fast slots per bucket

// init per-bucket cursors to raw region bases (int2 units); ccur[255] = ext counter
__global__ __launch_bounds__(256) void initcur(int* __restrict__ ccur, int nbuck) {
    int t = threadIdx.x;
    if (t < nbuck) ccur[t] = t * CAPR;
    if (t == 255) ccur[255] = 0;
}

// pass 1: block-local counting sort into coarse buckets; coalesced run writes.
// raw edge: x = src | (dst&511)<<17 ; y = bits(ew)
__global__ __launch_bounds__(512) void bucket1(const int* __restrict__ src,
                                               const int* __restrict__ dst,
                                               const float* __restrict__ ew,
                                               int* __restrict__ ccur,
                                               int2* __restrict__ pairs2,
                                               int E, int nbuck) {
    __shared__ int hist[512];
    __shared__ int lbase[512];
    __shared__ int gbase[512];
    __shared__ int wsum[8];
    __shared__ int w0s[PB];
    __shared__ int w1s[PB];
    __shared__ unsigned char bids[PB];
    int t = threadIdx.x;
    hist[t] = 0;
    __syncthreads();
    int e0 = blockIdx.x * PB;
    int cnt = min(PB, E - e0);
    int b[8], lr[8], w0[8], w1[8];
    int i8 = t * 8;
    bool full8 = (i8 + 8 <= cnt);
    if (full8) {
        int4   sa = *(const int4*)&src[e0 + i8];
        int4   sb = *(const int4*)&src[e0 + i8 + 4];
        int4   da = *(const int4*)&dst[e0 + i8];
        int4   db = *(const int4*)&dst[e0 + i8 + 4];
        float4 wa = *(const float4*)&ew[e0 + i8];
        float4 wb = *(const float4*)&ew[e0 + i8 + 4];
        int ss[8] = {sa.x, sa.y, sa.z, sa.w, sb.x, sb.y, sb.z, sb.w};
        int ds[8] = {da.x, da.y, da.z, da.w, db.x, db.y, db.z, db.w};
        float wv[8] = {wa.x, wa.y, wa.z, wa.w, wb.x, wb.y, wb.z, wb.w};
#pragma unroll
        for (int k = 0; k < 8; ++k) {
            b[k]  = ds[k] >> BSH;
            w0[k] = ss[k] | ((ds[k] & (BSZ - 1)) << 17);
            w1[k] = __float_as_int(wv[k]);
            lr[k] = atomicAdd(&hist[b[k]], 1);
        }
    } else {
#pragma unroll
        for (int k = 0; k < 8; ++k) {
            int idx = i8 + k;
            if (idx < cnt) {
                int d = dst[e0 + idx];
                b[k]  = d >> BSH;
                w0[k] = src[e0 + idx] | ((d & (BSZ - 1)) << 17);
                w1[k] = __float_as_int(ew[e0 + idx]);
                lr[k] = atomicAdd(&hist[b[k]], 1);
            }
        }
    }
    __syncthreads();
    int hv = hist[t];
    // wave-level shfl scan (2 barriers instead of 18)
    int lane = t & 63, wv8 = t >> 6;
    int s = hv;
#pragma unroll
    for (int off = 1; off < 64; off <<= 1) {
        int u = __shfl_up(s, off, 64);
        if (lane >= off) s += u;
    }
    if (lane == 63) wsum[wv8] = s;
    __syncthreads();
    int woff = 0;
#pragma unroll
    for (int w = 0; w < 8; ++w) { int x = wsum[w]; if (w < wv8) woff += x; }
    int excl = s + woff - hv;
    lbase[t] = excl;
    if (t < nbuck && hv > 0) gbase[t] = atomicAdd(&ccur[t], hv);
    __syncthreads();
#pragma unroll
    for (int k = 0; k < 8; ++k) {
        int idx = i8 + k;
        if (idx < cnt) {
            int slot = lbase[b[k]] + lr[k];
            w0s[slot] = w0[k];
            w1s[slot] = w1[k];
            bids[slot] = (unsigned char)b[k];
        }
    }
    __syncthreads();
    for (int i = t; i < cnt; i += 512) {
        int bb = bids[i];
        int pos = gbase[bb] + (i - lbase[bb]);
        pairs2[pos] = make_int2(w0s[i], w1s[i]);
    }
}

// fused pass 2, de-staged, pad-only zeroing: pass A counts+deg; pass B
// fresh-rank scatter to fastU; epilogue writes self-edge then zeros ONLY each
// node's pad slots [tot, min(pc,32)) (~6 avg) — no full-table fill, no extra
// barrier. tiers 16/24/32(+ext); code in bits 29-30 of extRng.x.
__global__ __launch_bounds__(512) void sort2(const int2* __restrict__ pairs2,
                                             unsigned int* __restrict__ fastU,
                                             const int* __restrict__ ccur,
                                             int2* __restrict__ extRng,
                                             unsigned int* __restrict__ extU,
                                             int* __restrict__ gext,
                                             float* __restrict__ dis,
                                             int N, int nbuck) {
    __shared__ int cnt[512];
    __shared__ float sdeg[512];
    __shared__ int cur[512];
    __shared__ int ebase[512];
    int b = blockIdx.x;
    int t = threadIdx.x;
    int baseR = b * CAPR;          // raw int2 units
    int baseF = b * FASTU;         // fast-table uint units
    int cntb = min(ccur[b] - baseR, CAPR);
    cnt[t] = 0;
    sdeg[t] = 0.0f;
    cur[t] = 0;
    __syncthreads();
    for (int i = t; i < cntb; i += 512) {
        int2 p = pairs2[baseR + i];
        int dl = (p.x >> 17) & (BSZ - 1);
        atomicAdd(&cnt[dl], 1);
        atomicAdd(&sdeg[dl], __int_as_float(p.y));
    }
    __syncthreads();
    int node = (b << BSH) + t;
    int cntv = cnt[t];
    int tot  = cntv + 1;                       // +1 self-edge
    int pc;
    if (tot <= 16)      pc = 16;
    else if (tot <= 24) pc = 24;
    else                pc = (tot + 31) & ~31;
    int code = (pc == 16) ? 0 : (pc == 24) ? 1 : 2;
    int extLen = (pc > 32) ? (pc - 32) : 0;
    int extBase = 0;
    if (node < N && extLen > 0) extBase = atomicAdd(gext, extLen);  // rare
    float dloc = rsqrtf(sdeg[t] + 1.0f);
    __syncthreads();
    sdeg[t]  = dloc;               // bucket-local dis
    ebase[t] = extBase;
    if (node < N) {
        extRng[node] = make_int2(extBase | (code << 29), extBase + extLen);
        dis[node]    = dloc;
    }
    __syncthreads();
    for (int i = t; i < cntb; i += 512) {
        int2 p = pairs2[baseR + i];
        int dl = (p.x >> 17) & (BSZ - 1);
        int s  = p.x & 0x1FFFF;
        int rank = atomicAdd(&cur[dl], 1);     // fresh ranks (uniqueness suffices)
        float w = __int_as_float(p.y) * sdeg[dl];   // ew * dis[dst]
        unsigned int h = (unsigned int)__half_as_ushort(__float2half_rn(w));
        unsigned int packed = ((unsigned int)s << 15) | ((h + 1u) >> 1);
        if (rank < 32) fastU[baseF + dl * 32 + rank] = packed;
        else           extU[ebase[dl] + rank - 32]   = packed;
    }
    __syncthreads();
    if (node < N) {
        unsigned int h = (unsigned int)__half_as_ushort(__float2half_rn(dloc));
        unsigned int selfp = ((unsigned int)node << 15) | ((h + 1u) >> 1);
        if (cntv < 32) fastU[baseF + t * 32 + cntv] = selfp;
        else           extU[extBase + cntv - 32]    = selfp;
        int capped = min(pc, 32);
        for (int i = tot; i < capped; ++i) fastU[baseF + t * 32 + i] = 0u;
        for (int i = cntv + 1 - 32; i < extLen; ++i) extU[extBase + i] = 0u;
    }
}

// Hb = dis * (X @ W) -> fp16; X is fp32 (layer 1) or fp16 (layer 2)
template<int HIN>
__global__ __launch_bounds__(256) void gemm64h(const void* __restrict__ Xv,
                                               const float* __restrict__ W,
                                               const float* __restrict__ dis,
                                               __half* __restrict__ Hb, int n) {
    __shared__ float Ws[64 * 64];
    __shared__ float Xs[16 * 64];
    for (int t = threadIdx.x; t < 64 * 64; t += 256) Ws[t] = W[t];
    int row0 = blockIdx.x * 16;
    for (int t = threadIdx.x; t < 16 * 64; t += 256) {
        int r = row0 + (t >> 6);
        float v = 0.0f;
        if (r < n) {
            if constexpr (HIN) v = __half2float(((const __half*)Xv)[r * 64 + (t & 63)]);
            else               v = ((const float*)Xv)[r * 64 + (t & 63)];
        }
        Xs[t] = v;
    }
    __syncthreads();
    int r  = threadIdx.x >> 4;
    int jc = (threadIdx.x & 15) * 4;
    float4 acc = make_float4(0.f, 0.f, 0.f, 0.f);
#pragma unroll
    for (int k = 0; k < 64; ++k) {
        float xv = Xs[r * 64 + k];
        float4 w = *(const float4*)&Ws[k * 64 + jc];
        acc.x += xv * w.x; acc.y += xv * w.y; acc.z += xv * w.z; acc.w += xv * w.w;
    }
    int rr = row0 + r;
    if (rr < n) {
        float ds = dis[rr];
        ushort4 pk;
        pk.x = __half_as_ushort(__float2half(ds * acc.x));
        pk.y = __half_as_ushort(__float2half(ds * acc.y));
        pk.z = __half_as_ushort(__float2half(ds * acc.z));
        pk.w = __half_as_ushort(__float2half(ds * acc.w));
        *(ushort4*)&Hb[rr * 64 + jc] = pk;
    }
}

// accumulate one 32-slot ext group (fp16 packed, 4 independent row gathers)
__device__ __forceinline__ void acc_group(unsigned int pv, int g, int fl,
                                          const __half* __restrict__ Hb,
                                          __half2 a0[4], __half2 a1[4],
                                          __half2 a2[4], __half2 a3[4]) {
    unsigned int q0 = __shfl(pv, g, 64);
    unsigned int q1 = __shfl(pv, g + 8, 64);
    unsigned int q2 = __shfl(pv, g + 16, 64);
    unsigned int q3 = __shfl(pv, g + 24, 64);
    uint4 r0 = *(const uint4*)(Hb + (size_t)(q0 >> 15) * 64 + fl);
    uint4 r1 = *(const uint4*)(Hb + (size_t)(q1 >> 15) * 64 + fl);
    uint4 r2 = *(const uint4*)(Hb + (size_t)(q2 >> 15) * 64 + fl);
    uint4 r3 = *(const uint4*)(Hb + (size_t)(q3 >> 15) * 64 + fl);
    __half2 w0 = __half2half2(__ushort_as_half((unsigned short)((q0 & 0x7FFFu) << 1)));
    __half2 w1 = __half2half2(__ushort_as_half((unsigned short)((q1 & 0x7FFFu) << 1)));
    __half2 w2 = __half2half2(__ushort_as_half((unsigned short)((q2 & 0x7FFFu) << 1)));
    __half2 w3 = __half2half2(__ushort_as_half((unsigned short)((q3 & 0x7FFFu) << 1)));
    const __half2* h0 = (const __half2*)&r0;
    const __half2* h1 = (const __half2*)&r1;
    const __half2* h2 = (const __half2*)&r2;
    const __half2* h3 = (const __half2*)&r3;
#pragma unroll
    for (int k = 0; k < 4; ++k) {
        a0[k] = __hfma2(w0, h0[k], a0[k]);
        a1[k] = __hfma2(w1, h1[k], a1[k]);
        a2[k] = __hfma2(w2, h2[k], a2[k]);
        a3[k] = __hfma2(w3, h3[k], a3[k]);
    }
}

// one wave per node; fixed fast slots; three-tier 16/24/32 pad (wave-uniform
// skip of rows q2 and/or q3); ext tail rare — r18 form (er off r0/r1 path)
template<int HOUT>
__global__ __launch_bounds__(256) void gather64(const unsigned int* __restrict__ fastU,
                                                const unsigned int* __restrict__ extU,
                                                const int2* __restrict__ extRng,
                                                const __half* __restrict__ Hb,
                                                void* __restrict__ OUTv, int N) {
    int node = blockIdx.x * 4 + (threadIdx.x >> 6);
    if (node >= N) return;
    int lane = threadIdx.x & 63;
    int g    = lane >> 3;          // edge sub-slot 0..7
    int fl   = (lane & 7) * 8;     // features fl..fl+7
    int l31  = lane & 31;
    int fbase = (node >> BSH) * FASTU + (node & (BSZ - 1)) * 32;
    unsigned int pv = fastU[fbase + l31];
    int2 er = extRng[node];        // independent load, off critical path
    int code = ((unsigned int)er.x >> 29) & 3;   // 0:16, 1:24, 2:32(+ext)
    int eb = er.x & 0x1FFFFFFF;
    __half2 z = __float2half2_rn(0.0f);
    __half2 a0[4] = {z, z, z, z};
    __half2 a1[4] = {z, z, z, z};
    __half2 a2[4] = {z, z, z, z};
    __half2 a3[4] = {z, z, z, z};
    {
        unsigned int q0 = __shfl(pv, g, 64);
        unsigned int q1 = __shfl(pv, g + 8, 64);
        unsigned int q2 = __shfl(pv, g + 16, 64);
        unsigned int q3 = __shfl(pv, g + 24, 64);
        uint4 r0 = *(const uint4*)(Hb + (size_t)(q0 >> 15) * 64 + fl);
        uint4 r1 = *(const uint4*)(Hb + (size_t)(q1 >> 15) * 64 + fl);
        uint4 r2, r3;
        if (code >= 1) r2 = *(const uint4*)(Hb + (size_t)(q2 >> 15) * 64 + fl);
        if (code >= 2) r3 = *(const uint4*)(Hb + (size_t)(q3 >> 15) * 64 + fl);
        __half2 w0 = __half2half2(__ushort_as_half((unsigned short)((q0 & 0x7FFFu) << 1)));
        __half2 w1 = __half2half2(__ushort_as_half((unsigned short)((q1 & 0x7FFFu) << 1)));
        const __half2* h0 = (const __half2*)&r0;
        const __half2* h1 = (const __half2*)&r1;
#pragma unroll
        for (int k = 0; k < 4; ++k) {
            a0[k] = __hfma2(w0, h0[k], a0[k]);
            a1[k] = __hfma2(w1, h1[k], a1[k]);
        }
        if (code >= 1) {
            __half2 w2 = __half2half2(__ushort_as_half((unsigned short)((q2 & 0x7FFFu) << 1)));
            const __half2* h2 = (const __half2*)&r2;
#pragma unroll
            for (int k = 0; k < 4; ++k) a2[k] = __hfma2(w2, h2[k], a2[k]);
        }
        if (code >= 2) {
            __half2 w3 = __half2half2(__ushort_as_half((unsigned short)((q3 & 0x7FFFu) << 1)));
            const __half2* h3 = (const __half2*)&r3;
#pragma unroll
            for (int k = 0; k < 4; ++k) a3[k] = __hfma2(w3, h3[k], a3[k]);
        }
    }
    for (int e = eb; e < er.y; e += 32)       // rare overflow tail (zero-padded)
        acc_group(extU[e + l31], g, fl, Hb, a0, a1, a2, a3);
    __half2 a[4];
#pragma unroll
    for (int k = 0; k < 4; ++k)
        a[k] = __hadd2(__hadd2(a0[k], a1[k]), __hadd2(a2[k], a3[k]));
    // fp16 butterfly across edge sub-slots (flip lane bits 3,4,5)
#pragma unroll
    for (int m = 8; m < 64; m <<= 1) {
#pragma unroll
        for (int k = 0; k < 4; ++k) {
            unsigned u = __shfl_xor(*(unsigned*)&a[k], m, 64);
            a[k] = __hadd2(a[k], *(__half2*)&u);
        }
    }
    // lanes g=0 write features fl..fl+3, g=1 write fl+4..fl+7
    if (g < 2) {
        int o = g * 2;
        float2 f0 = __half22float2(a[o]);
        float2 f1 = __half22float2(a[o + 1]);
        float rx = fmaxf(f0.x, 0.0f), ry = fmaxf(f0.y, 0.0f);
        float rz = fmaxf(f1.x, 0.0f), rw = fmaxf(f1.y, 0.0f);
        if constexpr (HOUT) {
            ushort4 pk;
            pk.x = __half_as_ushort(__float2half(rx));
            pk.y = __half_as_ushort(__float2half(ry));
            pk.z = __half_as_ushort(__float2half(rz));
            pk.w = __half_as_ushort(__float2half(rw));
            *(ushort4*)&((__half*)OUTv)[node * 64 + fl + g * 4] = pk;
        } else {
            float4 vv = make_float4(rx, ry, rz, rw);
            *(float4*)&((float*)OUTv)[node * 64 + fl + g * 4] = vv;
        }
    }
}

extern "C" void kernel_launch(void* const* d_in, const int* in_sizes, int n_in,
                              void* d_out, int out_size, void* d_ws, size_t ws_size,
                              hipStream_t stream) {
    const float* x  = (const float*)d_in[0];
    const int*   ei = (const int*)d_in[1];   // [2, E] int32
    const float* ew = (const float*)d_in[2];
    const float* W0 = (const float*)d_in[3];
    const float* W1 = (const float*)d_in[4];
    float* out = (float*)d_out;

    const int N = in_sizes[0] / D;           // 100000
    const int E = in_sizes[2];               // 1600000
    const int* src = ei;
    const int* dst = ei + E;

    const int nbuck = (N + BSZ - 1) >> BSH;  // 196
    const int Na = (N + 1 + 255) & ~255;

    // layout (ints): dis[Na] | extRng[2*Na] | ccur[1024] |
    //                pairs2 raw [nbuck*CAPR int2] (x1h aliases after sort2) |
    //                fastU [nbuck*FASTU uints] | Hb[64N halves] | extU[262144]
    float* dis     = (float*)d_ws;
    int2*  extRng  = (int2*)((int*)d_ws + Na);
    int*   ccur    = (int*)d_ws + 3 * Na;
    int2*  pairs2  = (int2*)((int*)d_ws + 3 * Na + 1024);
    unsigned int* fastU = (unsigned int*)(pairs2 + (size_t)nbuck * CAPR);
    __half* Hb     = (__half*)(fastU + (size_t)nbuck * FASTU);
    unsigned int* extU = (unsigned int*)(Hb + (size_t)N * D);
    __half* x1h    = (__half*)pairs2;        // aliases raw (dead after sort2)

    const int nb1 = (E + PB - 1) / PB;       // 391

    // --- build node-sorted, norm-folded, packed, fixed-slot edge table + dis ---
    initcur<<<1, 256, 0, stream>>>(ccur, nbuck);
    bucket1<<<nb1, 512, 0, stream>>>(src, dst, ew, ccur, pairs2, E, nbuck);
    sort2<<<nbuck, 512, 0, stream>>>(pairs2, fastU, ccur, extRng, extU,
                                     ccur + 255, dis, N, nbuck);

    const int gemm_grid   = (N + 15) / 16;
    const int gather_grid = (N + 3) / 4;

    // --- layer 1: fp16 intermediate x1h ---
    gemm64h<0><<<gemm_grid, 256, 0, stream>>>(x, W0, dis, Hb, N);
    gather64<1><<<gather_grid, 256, 0, stream>>>(fastU, extU, extRng, Hb, x1h, N);

    // --- layer 2: fp32 output ---
    gemm64h<1><<<gemm_grid, 256, 0, stream>>>(x1h, W1, dis, Hb, N);
    gather64<0><<<gather_grid, 256, 0, stream>>>(fastU, extU, extRng, Hb, out, N);
}